// Round 14
// baseline (16213.551 us; speedup 1.0000x reference)
//
#include <hip/hip_runtime.h>

// MultiScaleGRU: T=8192, NINP=128, NSTATE=1024, NCH=4, GH=256, NLAYER=3, NCLASS=10
#define T_SEQ  8192
#define NST    1024
#define GHH    256
#define LD_IG  3072      // 4 channels * 768 ig columns
#define C_CH   512       // pipeline chunk length
#define NCHUNK 16
#define NDIAG  18        // NCHUNK + NLAYER - 1

typedef _Float16 half8 __attribute__((ext_vector_type(8)));
typedef float f32x4 __attribute__((ext_vector_type(4)));

#define MFMA16(a, b, c) __builtin_amdgcn_mfma_f32_16x16x32_f16(a, b, c, 0, 0, 0)

__device__ __forceinline__ float sigmoid_f(float x) {
  return 1.0f / (1.0f + __expf(-x));
}
__device__ __forceinline__ float tanh_f(float x) {
  float ax = fabsf(x);
  float e = __expf(-2.0f * ax);
  float t = (1.0f - e) / (1.0f + e);
  return copysignf(t, x);
}

// ---------------------------------------------------------------------------
// Prep: whh [3,4,768,256] f32 -> f16 MFMA B-fragment cache (R7/R10-verified).
// Block nb = g*16+ub covers gate g (r/z/n), units ub*16 + (lane&15);
// chunk kc covers k = kc*32 + (lane>>4)*8 + e.
// ---------------------------------------------------------------------------
__global__ __launch_bounds__(256) void prep_whh(const float* __restrict__ whh,
                                                half8* __restrict__ wB)
{
  const int idx = blockIdx.x * 256 + threadIdx.x;   // 0 .. 294911
  const int lc  = idx / 24576;                      // layer*4+ch
  const int rem = idx - lc * 24576;
  const int g_id = rem >> 6, l = rem & 63;
  const int nb = g_id >> 3, kc = g_id & 7;
  const int g = nb >> 4, ub = nb & 15;
  const int n = l & 15, kg = l >> 4;
  const int row = g * 256 + ub * 16 + n;
  const int col = kc * 32 + kg * 8;
  const float* src = whh + (size_t)lc * 196608 + (size_t)row * 256 + col;
  float4 x0 = *reinterpret_cast<const float4*>(src);
  float4 x1 = *reinterpret_cast<const float4*>(src + 4);
  half8 o;
  o[0] = (_Float16)x0.x; o[1] = (_Float16)x0.y;
  o[2] = (_Float16)x0.z; o[3] = (_Float16)x0.w;
  o[4] = (_Float16)x1.x; o[5] = (_Float16)x1.y;
  o[6] = (_Float16)x1.z; o[7] = (_Float16)x1.w;
  wB[idx] = o;
}

// ---------------------------------------------------------------------------
// Weight f32 -> f16 converter (row-major, layout-preserving). n8 = elems/8.
// ---------------------------------------------------------------------------
__global__ __launch_bounds__(256) void cvt_to_h(const float* __restrict__ src,
                                                _Float16* __restrict__ dst, int n8)
{
  const int i = blockIdx.x * 256 + threadIdx.x;
  if (i >= n8) return;
  float4 a = reinterpret_cast<const float4*>(src)[2 * i];
  float4 b = reinterpret_cast<const float4*>(src)[2 * i + 1];
  half8 o;
  o[0] = (_Float16)a.x; o[1] = (_Float16)a.y; o[2] = (_Float16)a.z; o[3] = (_Float16)a.w;
  o[4] = (_Float16)b.x; o[5] = (_Float16)b.y; o[6] = (_Float16)b.z; o[7] = (_Float16)b.w;
  reinterpret_cast<half8*>(dst)[i] = o;
}

// ---------------------------------------------------------------------------
// f16-MFMA GEMM (R11-verified): C[M,N] = epi(A[M,K] @ W[N,K]^T).
// ---------------------------------------------------------------------------
template<int EPI, bool RELU>
__global__ __launch_bounds__(256) void gemm_h(
    const float* __restrict__ A, const _Float16* __restrict__ Wh,
    const float* __restrict__ bias, const float* __restrict__ R,
    float* __restrict__ C, int M, int N, int K,
    const float* __restrict__ log_s)
{
  __shared__ _Float16 As[64][40];
  __shared__ _Float16 Ws[64][40];
  const int t = threadIdx.x;
  const int bm = blockIdx.x * 64, bn = blockIdx.y * 64;
  const int wave = t >> 6, l = t & 63;
  const int wm = (wave & 1) * 32, wn = (wave >> 1) * 32;
  const int sr = t >> 2, sc = (t & 3) * 8;
  const int fr = l & 15, fk = (l >> 4) * 8;

  f32x4 acc00 = {0.f, 0.f, 0.f, 0.f}, acc01 = acc00, acc10 = acc00, acc11 = acc00;

  const float* Ap     = A  + (size_t)(bm + sr) * K + sc;
  const _Float16* Wp  = Wh + (size_t)(bn + sr) * K + sc;

  for (int k0 = 0; k0 < K; k0 += 32) {
    float4 a0 = *reinterpret_cast<const float4*>(Ap + k0);
    float4 a1 = *reinterpret_cast<const float4*>(Ap + k0 + 4);
    half8 av;
    av[0] = (_Float16)a0.x; av[1] = (_Float16)a0.y;
    av[2] = (_Float16)a0.z; av[3] = (_Float16)a0.w;
    av[4] = (_Float16)a1.x; av[5] = (_Float16)a1.y;
    av[6] = (_Float16)a1.z; av[7] = (_Float16)a1.w;
    *reinterpret_cast<half8*>(&As[sr][sc]) = av;
    *reinterpret_cast<half8*>(&Ws[sr][sc]) =
        *reinterpret_cast<const half8*>(Wp + k0);
    __syncthreads();
    half8 af0 = *reinterpret_cast<const half8*>(&As[wm + fr][fk]);
    half8 af1 = *reinterpret_cast<const half8*>(&As[wm + 16 + fr][fk]);
    half8 bf0 = *reinterpret_cast<const half8*>(&Ws[wn + fr][fk]);
    half8 bf1 = *reinterpret_cast<const half8*>(&Ws[wn + 16 + fr][fk]);
    acc00 = MFMA16(af0, bf0, acc00);
    acc01 = MFMA16(af0, bf1, acc01);
    acc10 = MFMA16(af1, bf0, acc10);
    acc11 = MFMA16(af1, bf1, acc11);
    __syncthreads();
  }

#define EPI_STORE(ac, mi, ni) { \
    const int n_ = bn + wn + (ni) * 16 + fr; \
    const float bv = bias[n_]; \
    float sc_ = 1.f; \
    if (EPI == 1) { \
      float lsv = log_s[n_ / 768]; \
      lsv = fminf(fmaxf(lsv, -10.f), 10.f); \
      sc_ = __expf(-lsv); \
    } \
    _Pragma("unroll") \
    for (int q = 0; q < 4; ++q) { \
      const int m_ = bm + wm + (mi) * 16 + (l >> 4) * 4 + q; \
      float v = ac[q]; \
      if (EPI == 1) v *= sc_; \
      v += bv; \
      if (EPI == 2) v += R[(size_t)m_ * N + n_]; \
      if (RELU) v = fmaxf(v, 0.f); \
      C[(size_t)m_ * N + n_] = v; \
    } }
  EPI_STORE(acc00, 0, 0) EPI_STORE(acc01, 0, 1)
  EPI_STORE(acc10, 1, 0) EPI_STORE(acc11, 1, 1)
#undef EPI_STORE
}

// ---------------------------------------------------------------------------
// LayerNorm over 1024 features, one block per row (unchanged).
// ---------------------------------------------------------------------------
template<bool ADD>
__global__ __launch_bounds__(256) void ln_kernel(const float* __restrict__ X,
                                                 const float* __restrict__ Yad,
                                                 float* __restrict__ O)
{
  const int row = blockIdx.x, t = threadIdx.x;
  float4 v = reinterpret_cast<const float4*>(X + (size_t)row * NST)[t];
  if (ADD) {
    float4 w = reinterpret_cast<const float4*>(Yad + (size_t)row * NST)[t];
    v.x += w.x; v.y += w.y; v.z += w.z; v.w += w.w;
  }
  float s  = v.x + v.y + v.z + v.w;
  float ss = v.x * v.x + v.y * v.y + v.z * v.z + v.w * v.w;
#pragma unroll
  for (int m = 1; m < 64; m <<= 1) {
    s  += __shfl_xor(s, m, 64);
    ss += __shfl_xor(ss, m, 64);
  }
  __shared__ float ps[4], pss[4];
  const int wv = t >> 6;
  if ((t & 63) == 0) { ps[wv] = s; pss[wv] = ss; }
  __syncthreads();
  s  = ps[0] + ps[1] + ps[2] + ps[3];
  ss = pss[0] + pss[1] + pss[2] + pss[3];
  const float mean = s * (1.f / 1024.f);
  const float var  = ss * (1.f / 1024.f) - mean * mean;
  const float rstd = rsqrtf(var + 1e-5f);
  v.x = (v.x - mean) * rstd; v.y = (v.y - mean) * rstd;
  v.z = (v.z - mean) * rstd; v.w = (v.w - mean) * rstd;
  reinterpret_cast<float4*>(O + (size_t)row * NST)[t] = v;
}

// ---------------------------------------------------------------------------
// Fused double-LN: O = LN(Y + LN(X)) per row (unchanged).
// ---------------------------------------------------------------------------
__global__ __launch_bounds__(256) void ln2_kernel(const float* __restrict__ Y,
                                                  const float* __restrict__ X,
                                                  float* __restrict__ O)
{
  const int row = blockIdx.x, t = threadIdx.x;
  const int wv = t >> 6;
  __shared__ float ps[4], pss[4], ps2[4], pss2[4];

  float4 xv = reinterpret_cast<const float4*>(X + (size_t)row * NST)[t];
  float s  = xv.x + xv.y + xv.z + xv.w;
  float ss = xv.x * xv.x + xv.y * xv.y + xv.z * xv.z + xv.w * xv.w;
#pragma unroll
  for (int m = 1; m < 64; m <<= 1) {
    s += __shfl_xor(s, m, 64); ss += __shfl_xor(ss, m, 64);
  }
  if ((t & 63) == 0) { ps[wv] = s; pss[wv] = ss; }
  __syncthreads();
  s = ps[0] + ps[1] + ps[2] + ps[3];
  ss = pss[0] + pss[1] + pss[2] + pss[3];
  float mean = s * (1.f / 1024.f);
  float var  = ss * (1.f / 1024.f) - mean * mean;
  float rstd = rsqrtf(var + 1e-5f);

  float4 yv = reinterpret_cast<const float4*>(Y + (size_t)row * NST)[t];
  float4 v;
  v.x = yv.x + (xv.x - mean) * rstd;
  v.y = yv.y + (xv.y - mean) * rstd;
  v.z = yv.z + (xv.z - mean) * rstd;
  v.w = yv.w + (xv.w - mean) * rstd;

  s  = v.x + v.y + v.z + v.w;
  ss = v.x * v.x + v.y * v.y + v.z * v.z + v.w * v.w;
#pragma unroll
  for (int m = 1; m < 64; m <<= 1) {
    s += __shfl_xor(s, m, 64); ss += __shfl_xor(ss, m, 64);
  }
  if ((t & 63) == 0) { ps2[wv] = s; pss2[wv] = ss; }
  __syncthreads();
  s = ps2[0] + ps2[1] + ps2[2] + ps2[3];
  ss = pss2[0] + pss2[1] + pss2[2] + pss2[3];
  mean = s * (1.f / 1024.f);
  var  = ss * (1.f / 1024.f) - mean * mean;
  rstd = rsqrtf(var + 1e-5f);
  v.x = (v.x - mean) * rstd; v.y = (v.y - mean) * rstd;
  v.z = (v.z - mean) * rstd; v.w = (v.w - mean) * rstd;
  reinterpret_cast<float4*>(O + (size_t)row * NST)[t] = v;
}

// ---------------------------------------------------------------------------
// ScaleGRU scan — diagonal MFMA, GATE-IN-WAVE v2.
// Wave w owns blocks {w, w+8, w+16, w+24, w+32, w+40}: r,z,n pre-acts for
// units u1=16w+l and u2=128+16w+l all land in lanes l<16 of wave w
// (D col = lane&15; uniform-A -> acc[0] valid). Gates computed in-register:
// no hg buffer, no second barrier. h double-buffered (512B x2) so ONE
// lgkm-only barrier/step is race-free: all writes to buf[(t+1)&1] precede
// barrier(t); step t+1 writes the other buffer.
// ---------------------------------------------------------------------------
#define SCAN_BAR() asm volatile("s_waitcnt lgkmcnt(0)\n\ts_barrier" ::: "memory")

#define DECLB(i) half8 B##i##_0, B##i##_1, B##i##_2, B##i##_3, \
                       B##i##_4, B##i##_5, B##i##_6, B##i##_7;
#define LOADBn(i, nb) \
  B##i##_0 = wpB[((nb)*8+0)*64]; B##i##_1 = wpB[((nb)*8+1)*64]; \
  B##i##_2 = wpB[((nb)*8+2)*64]; B##i##_3 = wpB[((nb)*8+3)*64]; \
  B##i##_4 = wpB[((nb)*8+4)*64]; B##i##_5 = wpB[((nb)*8+5)*64]; \
  B##i##_6 = wpB[((nb)*8+6)*64]; B##i##_7 = wpB[((nb)*8+7)*64];

#define KCSTEP(kc) { \
  half8 a = hp[(kc) * 4]; \
  a0 = MFMA16(a, B0_##kc, a0); a1 = MFMA16(a, B1_##kc, a1); \
  a2 = MFMA16(a, B2_##kc, a2); a3 = MFMA16(a, B3_##kc, a3); \
  a4 = MFMA16(a, B4_##kc, a4); a5 = MFMA16(a, B5_##kc, a5); }

__global__ __attribute__((amdgpu_flat_work_group_size(512, 512)))
void scan_diag(
    const half8* __restrict__ wB,     // frag cache [3*4][384][64]
    const float* __restrict__ gbn,    // [3,4,256]
    const float* __restrict__ gls,    // [3,4]
    const float* __restrict__ igb,    // [3][C_CH,3072]
    const float* __restrict__ h0,     // [256]
    float* __restrict__ hst,          // [3*4*256] carried h state
    float* __restrict__ yb,           // [3][C_CH,1024]
    int d)
{
  const int lidx = blockIdx.x >> 2;
  const int ch   = blockIdx.x & 3;
  const int c    = d - lidx;
  if (c < 0 || c >= NCHUNK) return;

  const int j = threadIdx.x;
  const int w = j >> 6, l = j & 63;
  const int lc = lidx * 4 + ch;
  const float* igc = igb + (size_t)lidx * (C_CH * LD_IG) + ch * 768;
  float* yc        = yb + (size_t)lidx * (C_CH * NST) + ch * GHH;

  // blocks {w, w+8, w+16, w+24, w+32, w+40}: (r,u1),(r,u2),(z,u1),(z,u2),(n,u1),(n,u2)
  const half8* wpB = wB + (size_t)lc * 24576 + l;
  DECLB(0) DECLB(1) DECLB(2) DECLB(3) DECLB(4) DECLB(5)
  LOADBn(0, w)      LOADBn(1, w + 8)  LOADBn(2, w + 16)
  LOADBn(3, w + 24) LOADBn(4, w + 32) LOADBn(5, w + 40)

  __shared__ __align__(16) _Float16 hsl[2][GHH];   // double-buffered h

  const bool glane = (l < 16);
  const int u1 = 16 * w + l;          // valid when glane
  const int u2 = 128 + 16 * w + l;

  float ls = gls[lc];
  ls = fminf(fmaxf(ls, -10.f), 10.f);
  const float inv_s = __expf(-ls);
  float bn1 = 0.f, bn2 = 0.f, h1 = 0.f, h2 = 0.f;
  float i1r = 0.f, i1z = 0.f, i1n = 0.f, i2r = 0.f, i2z = 0.f, i2n = 0.f;
  if (glane) {
    h1 = (c == 0) ? h0[u1] : hst[lc * GHH + u1];
    h2 = (c == 0) ? h0[u2] : hst[lc * GHH + u2];
    bn1 = gbn[lc * GHH + u1];
    bn2 = gbn[lc * GHH + u2];
    hsl[0][u1] = (_Float16)h1;
    hsl[0][u2] = (_Float16)h2;
    i1r = igc[u1]; i1z = igc[256 + u1]; i1n = igc[512 + u1];
    i2r = igc[u2]; i2z = igc[256 + u2]; i2n = igc[512 + u2];
  }
  SCAN_BAR();

  for (int t = 0; t < C_CH; ++t) {
    float n1r = 0.f, n1z = 0.f, n1n = 0.f, n2r = 0.f, n2z = 0.f, n2n = 0.f;
    if (glane && t + 1 < C_CH) {
      const float* p = igc + (size_t)(t + 1) * LD_IG;
      n1r = p[u1]; n1z = p[256 + u1]; n1n = p[512 + u1];
      n2r = p[u2]; n2z = p[256 + u2]; n2n = p[512 + u2];
    }
    const half8* hp = reinterpret_cast<const half8*>(hsl[t & 1]) + (l >> 4);
    f32x4 a0 = {0.f, 0.f, 0.f, 0.f}, a1 = a0, a2 = a0, a3 = a0, a4 = a0, a5 = a0;
    KCSTEP(0) KCSTEP(1) KCSTEP(2) KCSTEP(3)
    KCSTEP(4) KCSTEP(5) KCSTEP(6) KCSTEP(7)
    if (glane) {
      const float rg1 = sigmoid_f(i1r + a0[0]);
      const float zg1 = sigmoid_f(i1z + a2[0]);
      const float ng1 = tanh_f(i1n + rg1 * (a4[0] + bn1));
      const float hw1 = ng1 + zg1 * (h1 - ng1);
      h1 = (hw1 - h1) * inv_s + h1;
      const float rg2 = sigmoid_f(i2r + a1[0]);
      const float zg2 = sigmoid_f(i2z + a3[0]);
      const float ng2 = tanh_f(i2n + rg2 * (a5[0] + bn2));
      const float hw2 = ng2 + zg2 * (h2 - ng2);
      h2 = (hw2 - h2) * inv_s + h2;
      yc[(size_t)t * NST + u1] = h1;
      yc[(size_t)t * NST + u2] = h2;
      hsl[(t + 1) & 1][u1] = (_Float16)h1;
      hsl[(t + 1) & 1][u2] = (_Float16)h2;
    }
    SCAN_BAR();
    i1r = n1r; i1z = n1z; i1n = n1n;
    i2r = n2r; i2z = n2z; i2n = n2n;
  }
  if (glane) {
    hst[lc * GHH + u1] = h1;
    hst[lc * GHH + u2] = h2;
  }
}

// ---------------------------------------------------------------------------
// Classifier second GEMM: N=10, K=1024. One block per row (unchanged).
// ---------------------------------------------------------------------------
__global__ __launch_bounds__(256) void gemv_cls(const float* __restrict__ A,
                                                const float* __restrict__ W,
                                                const float* __restrict__ b,
                                                float* __restrict__ out)
{
  const int m = blockIdx.x, t = threadIdx.x;
  float4 a = reinterpret_cast<const float4*>(A + (size_t)m * NST)[t];
  float p[10];
#pragma unroll
  for (int n = 0; n < 10; ++n) {
    float4 w = reinterpret_cast<const float4*>(W + (size_t)n * NST)[t];
    p[n] = a.x * w.x + a.y * w.y + a.z * w.z + a.w * w.w;
  }
#pragma unroll
  for (int n = 0; n < 10; ++n)
#pragma unroll
    for (int msk = 1; msk < 64; msk <<= 1) p[n] += __shfl_xor(p[n], msk, 64);
  __shared__ float red[4][10];
  const int wv = t >> 6;
  if ((t & 63) == 0) {
#pragma unroll
    for (int n = 0; n < 10; ++n) red[wv][n] = p[n];
  }
  __syncthreads();
  if (t < 10) {
    float v = red[0][t] + red[1][t] + red[2][t] + red[3][t] + b[t];
    out[(size_t)m * 10 + t] = v;
  }
}

// ---------------------------------------------------------------------------
extern "C" void kernel_launch(void* const* d_in, const int* in_sizes, int n_in,
                              void* d_out, int out_size, void* d_ws, size_t ws_size,
                              hipStream_t stream) {
  const float* inputs = (const float*)d_in[0];
  const float* h0     = (const float*)d_in[1];
  // d_in[2] = yinit_guess: unused (exact solution independent of it)
  const float* enc_w1 = (const float*)d_in[3];
  const float* enc_b1 = (const float*)d_in[4];
  const float* enc_w2 = (const float*)d_in[5];
  const float* enc_b2 = (const float*)d_in[6];
  const float* gwih   = (const float*)d_in[7];   // [3,4,768,1024]
  const float* gwhh   = (const float*)d_in[8];   // [3,4,768,256]
  const float* gb     = (const float*)d_in[9];   // [3,4,768]
  const float* gbn    = (const float*)d_in[10];  // [3,4,256]
  const float* gls    = (const float*)d_in[11];  // [3,4,1]
  const float* mw1    = (const float*)d_in[12];
  const float* mb1    = (const float*)d_in[13];
  const float* mw2    = (const float*)d_in[14];
  const float* mb2    = (const float*)d_in[15];
  const float* cw1    = (const float*)d_in[16];
  const float* cb1    = (const float*)d_in[17];
  const float* cw2    = (const float*)d_in[18];
  const float* cb2    = (const float*)d_in[19];
  float* out = (float*)d_out;

  // ws layout (bytes) — tops out at ~151.8MB (< 162.3MB proven in R11)
  char* ws = (char*)d_ws;
  float* x0    = (float*)(ws);                        // [8192,1024] 33.5MB
  float* xr1   = (float*)(ws + 33554432ull);          // ring [2][C,1024] 4.2MB
  float* xr2   = (float*)(ws + 37748736ull);          // ring [2][C,1024] 4.2MB
  float* igbuf = (float*)(ws + 41943040ull);          // [3][C,3072] 18.9MB
  half8* gw16  = (half8*)(ws + 60817408ull);          // scan frag cache 4.7MB
  float* bufY  = (float*)(ws + 65536000ull);          // [3][C,1024] 6.3MB
  float* bufYn = (float*)(ws + 71827456ull);          // [C,1024] 2.1MB
  float* bufH  = (float*)(ws + 73924608ull);          // [C,1024] 2.1MB
  float* xitmp = (float*)(ws + 76021760ull);          // [C,1024] 2.1MB
  float* xf    = (float*)(ws + 78118912ull);          // [C,1024] 2.1MB
  float* clsH  = (float*)(ws + 80216064ull);          // [C,1024] 2.1MB
  float* hst   = (float*)(ws + 82313216ull);          // [3,4,256] 12KB
  _Float16* wf = (_Float16*)(ws + 82325504ull);       // f16 weights 35.9MB
  float* encS  = (float*)(ws + 118239232ull);         // encoder hidden 33.5MB

  // f16 weight sub-offsets (in halfs)
  _Float16* wh_enc1 = wf;                     // 1024x128
  _Float16* wh_enc2 = wf + 131072;            // 1024x1024
  _Float16* wh_wih  = wf + 1179648;           // 3x 3072x1024
  _Float16* wh_mw1  = wf + 10616832;          // 3x 1024x1024
  _Float16* wh_mw2  = wf + 13762560;          // 3x 1024x1024
  _Float16* wh_cw1  = wf + 16908288;          // 1024x1024

  const dim3 blk(256);
  const dim3 g_enc(8192 / 64, 1024 / 64);
  const dim3 g_ig(C_CH / 64, 3072 / 64);
  const dim3 g_mlp(C_CH / 64, 1024 / 64);

  auto xptr = [&](int lth, int c) -> float* {
    if (lth == 0) return x0 + (size_t)c * C_CH * NST;
    float* base = (lth == 1) ? xr1 : xr2;
    return base + (size_t)(c & 1) * C_CH * NST;
  };

  // scan frag cache + GEMM weight conversion
  prep_whh<<<dim3(1152), blk, 0, stream>>>(gwhh, gw16);
  cvt_to_h<<<dim3(64),   blk, 0, stream>>>(enc_w1, wh_enc1, 16384);
  cvt_to_h<<<dim3(512),  blk, 0, stream>>>(enc_w2, wh_enc2, 131072);
  cvt_to_h<<<dim3(4608), blk, 0, stream>>>(gwih,   wh_wih,  1179648);
  cvt_to_h<<<dim3(1536), blk, 0, stream>>>(mw1,    wh_mw1,  393216);
  cvt_to_h<<<dim3(1536), blk, 0, stream>>>(mw2,    wh_mw2,  393216);
  cvt_to_h<<<dim3(512),  blk, 0, stream>>>(cw1,    wh_cw1,  131072);

  // encoder (full T)
  gemm_h<0, true ><<<g_enc, blk, 0, stream>>>(inputs, wh_enc1, enc_b1, nullptr,
                                              encS, 8192, 1024, 128, nullptr);
  gemm_h<0, false><<<g_enc, blk, 0, stream>>>(encS, wh_enc2, enc_b2, nullptr,
                                              x0, 8192, 1024, 1024, nullptr);

  for (int d = 0; d < NDIAG; ++d) {
    // --- pre: ig(l, c) for every pair active at diagonal d ---
    for (int lth = 0; lth < 3; ++lth) {
      const int c = d - lth;
      if (c < 0 || c >= NCHUNK) continue;
      ln_kernel<false><<<dim3(C_CH), blk, 0, stream>>>(xptr(lth, c), nullptr, xitmp);
      gemm_h<1, false><<<g_ig, blk, 0, stream>>>(
          xitmp, wh_wih + (size_t)lth * 3145728, gb + (size_t)lth * 3072,
          nullptr, igbuf + (size_t)lth * C_CH * LD_IG, C_CH, 3072, 1024,
          gls + (size_t)lth * 4);
    }
    // --- scan diagonal: up to 12 (layer,channel) blocks in parallel ---
    scan_diag<<<dim3(12), dim3(512), 0, stream>>>(gw16, gbn, gls, igbuf,
                                                  h0, hst, bufY, d);
    // --- post: y -> next layer input (or classifier) per active pair ---
    for (int lth = 0; lth < 3; ++lth) {
      const int c = d - lth;
      if (c < 0 || c >= NCHUNK) continue;
      ln2_kernel<<<dim3(C_CH), blk, 0, stream>>>(
          bufY + (size_t)lth * C_CH * NST, xptr(lth, c), bufYn);
      gemm_h<0, true ><<<g_mlp, blk, 0, stream>>>(
          bufYn, wh_mw1 + (size_t)lth * 1048576, mb1 + (size_t)lth * 1024,
          nullptr, bufH, C_CH, 1024, 1024, nullptr);
      float* xnext = (lth < 2) ? xptr(lth + 1, c) : xf;
      gemm_h<2, false><<<g_mlp, blk, 0, stream>>>(
          bufH, wh_mw2 + (size_t)lth * 1048576, mb2 + (size_t)lth * 1024,
          bufYn, xnext, C_CH, 1024, 1024, nullptr);
      if (lth == 2) {   // classifier on this finished chunk
        gemm_h<0, true><<<g_mlp, blk, 0, stream>>>(
            xf, wh_cw1, cb1, nullptr, clsH, C_CH, 1024, 1024, nullptr);
        gemv_cls<<<dim3(C_CH), blk, 0, stream>>>(clsH, cw2, cb2,
                                                 out + (size_t)c * C_CH * 10);
      }
    }
  }
}

// Round 15
// 12041.479 us; speedup vs baseline: 1.3465x; 1.3465x over previous
//
#include <hip/hip_runtime.h>

// MultiScaleGRU: T=8192, NINP=128, NSTATE=1024, NCH=4, GH=256, NLAYER=3, NCLASS=10
#define T_SEQ  8192
#define NST    1024
#define GHH    256
#define LD_IG  3072      // 4 channels * 768 ig columns
#define C_CH   1024      // pipeline chunk length (R14 lesson: 512 chunks double
                         // dispatch count and halve GEMM occupancy -> +3ms)
#define NCHUNK 8
#define NDIAG  10        // NCHUNK + NLAYER - 1

typedef _Float16 half8 __attribute__((ext_vector_type(8)));
typedef float f32x4 __attribute__((ext_vector_type(4)));

#define MFMA16(a, b, c) __builtin_amdgcn_mfma_f32_16x16x32_f16(a, b, c, 0, 0, 0)

__device__ __forceinline__ float sigmoid_f(float x) {
  return 1.0f / (1.0f + __expf(-x));
}
__device__ __forceinline__ float tanh_f(float x) {
  float ax = fabsf(x);
  float e = __expf(-2.0f * ax);
  float t = (1.0f - e) / (1.0f + e);
  return copysignf(t, x);
}

// ---------------------------------------------------------------------------
// Prep: whh [3,4,768,256] f32 -> f16 MFMA B-fragment cache (R7/R10-verified).
// Block nb = g*16+ub covers gate g (r/z/n), units ub*16 + (lane&15);
// chunk kc covers k = kc*32 + (lane>>4)*8 + e.
// ---------------------------------------------------------------------------
__global__ __launch_bounds__(256) void prep_whh(const float* __restrict__ whh,
                                                half8* __restrict__ wB)
{
  const int idx = blockIdx.x * 256 + threadIdx.x;   // 0 .. 294911
  const int lc  = idx / 24576;                      // layer*4+ch
  const int rem = idx - lc * 24576;
  const int g_id = rem >> 6, l = rem & 63;
  const int nb = g_id >> 3, kc = g_id & 7;
  const int g = nb >> 4, ub = nb & 15;
  const int n = l & 15, kg = l >> 4;
  const int row = g * 256 + ub * 16 + n;
  const int col = kc * 32 + kg * 8;
  const float* src = whh + (size_t)lc * 196608 + (size_t)row * 256 + col;
  float4 x0 = *reinterpret_cast<const float4*>(src);
  float4 x1 = *reinterpret_cast<const float4*>(src + 4);
  half8 o;
  o[0] = (_Float16)x0.x; o[1] = (_Float16)x0.y;
  o[2] = (_Float16)x0.z; o[3] = (_Float16)x0.w;
  o[4] = (_Float16)x1.x; o[5] = (_Float16)x1.y;
  o[6] = (_Float16)x1.z; o[7] = (_Float16)x1.w;
  wB[idx] = o;
}

// ---------------------------------------------------------------------------
// Weight f32 -> f16 converter (row-major, layout-preserving). n8 = elems/8.
// ---------------------------------------------------------------------------
__global__ __launch_bounds__(256) void cvt_to_h(const float* __restrict__ src,
                                                _Float16* __restrict__ dst, int n8)
{
  const int i = blockIdx.x * 256 + threadIdx.x;
  if (i >= n8) return;
  float4 a = reinterpret_cast<const float4*>(src)[2 * i];
  float4 b = reinterpret_cast<const float4*>(src)[2 * i + 1];
  half8 o;
  o[0] = (_Float16)a.x; o[1] = (_Float16)a.y; o[2] = (_Float16)a.z; o[3] = (_Float16)a.w;
  o[4] = (_Float16)b.x; o[5] = (_Float16)b.y; o[6] = (_Float16)b.z; o[7] = (_Float16)b.w;
  reinterpret_cast<half8*>(dst)[i] = o;
}

// ---------------------------------------------------------------------------
// f16-MFMA GEMM (R11-verified): C[M,N] = epi(A[M,K] @ W[N,K]^T).
// ---------------------------------------------------------------------------
template<int EPI, bool RELU>
__global__ __launch_bounds__(256) void gemm_h(
    const float* __restrict__ A, const _Float16* __restrict__ Wh,
    const float* __restrict__ bias, const float* __restrict__ R,
    float* __restrict__ C, int M, int N, int K,
    const float* __restrict__ log_s)
{
  __shared__ _Float16 As[64][40];
  __shared__ _Float16 Ws[64][40];
  const int t = threadIdx.x;
  const int bm = blockIdx.x * 64, bn = blockIdx.y * 64;
  const int wave = t >> 6, l = t & 63;
  const int wm = (wave & 1) * 32, wn = (wave >> 1) * 32;
  const int sr = t >> 2, sc = (t & 3) * 8;
  const int fr = l & 15, fk = (l >> 4) * 8;

  f32x4 acc00 = {0.f, 0.f, 0.f, 0.f}, acc01 = acc00, acc10 = acc00, acc11 = acc00;

  const float* Ap     = A  + (size_t)(bm + sr) * K + sc;
  const _Float16* Wp  = Wh + (size_t)(bn + sr) * K + sc;

  for (int k0 = 0; k0 < K; k0 += 32) {
    float4 a0 = *reinterpret_cast<const float4*>(Ap + k0);
    float4 a1 = *reinterpret_cast<const float4*>(Ap + k0 + 4);
    half8 av;
    av[0] = (_Float16)a0.x; av[1] = (_Float16)a0.y;
    av[2] = (_Float16)a0.z; av[3] = (_Float16)a0.w;
    av[4] = (_Float16)a1.x; av[5] = (_Float16)a1.y;
    av[6] = (_Float16)a1.z; av[7] = (_Float16)a1.w;
    *reinterpret_cast<half8*>(&As[sr][sc]) = av;
    *reinterpret_cast<half8*>(&Ws[sr][sc]) =
        *reinterpret_cast<const half8*>(Wp + k0);
    __syncthreads();
    half8 af0 = *reinterpret_cast<const half8*>(&As[wm + fr][fk]);
    half8 af1 = *reinterpret_cast<const half8*>(&As[wm + 16 + fr][fk]);
    half8 bf0 = *reinterpret_cast<const half8*>(&Ws[wn + fr][fk]);
    half8 bf1 = *reinterpret_cast<const half8*>(&Ws[wn + 16 + fr][fk]);
    acc00 = MFMA16(af0, bf0, acc00);
    acc01 = MFMA16(af0, bf1, acc01);
    acc10 = MFMA16(af1, bf0, acc10);
    acc11 = MFMA16(af1, bf1, acc11);
    __syncthreads();
  }

#define EPI_STORE(ac, mi, ni) { \
    const int n_ = bn + wn + (ni) * 16 + fr; \
    const float bv = bias[n_]; \
    float sc_ = 1.f; \
    if (EPI == 1) { \
      float lsv = log_s[n_ / 768]; \
      lsv = fminf(fmaxf(lsv, -10.f), 10.f); \
      sc_ = __expf(-lsv); \
    } \
    _Pragma("unroll") \
    for (int q = 0; q < 4; ++q) { \
      const int m_ = bm + wm + (mi) * 16 + (l >> 4) * 4 + q; \
      float v = ac[q]; \
      if (EPI == 1) v *= sc_; \
      v += bv; \
      if (EPI == 2) v += R[(size_t)m_ * N + n_]; \
      if (RELU) v = fmaxf(v, 0.f); \
      C[(size_t)m_ * N + n_] = v; \
    } }
  EPI_STORE(acc00, 0, 0) EPI_STORE(acc01, 0, 1)
  EPI_STORE(acc10, 1, 0) EPI_STORE(acc11, 1, 1)
#undef EPI_STORE
}

// ---------------------------------------------------------------------------
// LayerNorm over 1024 features, one block per row (unchanged).
// ---------------------------------------------------------------------------
template<bool ADD>
__global__ __launch_bounds__(256) void ln_kernel(const float* __restrict__ X,
                                                 const float* __restrict__ Yad,
                                                 float* __restrict__ O)
{
  const int row = blockIdx.x, t = threadIdx.x;
  float4 v = reinterpret_cast<const float4*>(X + (size_t)row * NST)[t];
  if (ADD) {
    float4 w = reinterpret_cast<const float4*>(Yad + (size_t)row * NST)[t];
    v.x += w.x; v.y += w.y; v.z += w.z; v.w += w.w;
  }
  float s  = v.x + v.y + v.z + v.w;
  float ss = v.x * v.x + v.y * v.y + v.z * v.z + v.w * v.w;
#pragma unroll
  for (int m = 1; m < 64; m <<= 1) {
    s  += __shfl_xor(s, m, 64);
    ss += __shfl_xor(ss, m, 64);
  }
  __shared__ float ps[4], pss[4];
  const int wv = t >> 6;
  if ((t & 63) == 0) { ps[wv] = s; pss[wv] = ss; }
  __syncthreads();
  s  = ps[0] + ps[1] + ps[2] + ps[3];
  ss = pss[0] + pss[1] + pss[2] + pss[3];
  const float mean = s * (1.f / 1024.f);
  const float var  = ss * (1.f / 1024.f) - mean * mean;
  const float rstd = rsqrtf(var + 1e-5f);
  v.x = (v.x - mean) * rstd; v.y = (v.y - mean) * rstd;
  v.z = (v.z - mean) * rstd; v.w = (v.w - mean) * rstd;
  reinterpret_cast<float4*>(O + (size_t)row * NST)[t] = v;
}

// ---------------------------------------------------------------------------
// Fused double-LN: O = LN(Y + LN(X)) per row (unchanged).
// ---------------------------------------------------------------------------
__global__ __launch_bounds__(256) void ln2_kernel(const float* __restrict__ Y,
                                                  const float* __restrict__ X,
                                                  float* __restrict__ O)
{
  const int row = blockIdx.x, t = threadIdx.x;
  const int wv = t >> 6;
  __shared__ float ps[4], pss[4], ps2[4], pss2[4];

  float4 xv = reinterpret_cast<const float4*>(X + (size_t)row * NST)[t];
  float s  = xv.x + xv.y + xv.z + xv.w;
  float ss = xv.x * xv.x + xv.y * xv.y + xv.z * xv.z + xv.w * xv.w;
#pragma unroll
  for (int m = 1; m < 64; m <<= 1) {
    s += __shfl_xor(s, m, 64); ss += __shfl_xor(ss, m, 64);
  }
  if ((t & 63) == 0) { ps[wv] = s; pss[wv] = ss; }
  __syncthreads();
  s = ps[0] + ps[1] + ps[2] + ps[3];
  ss = pss[0] + pss[1] + pss[2] + pss[3];
  float mean = s * (1.f / 1024.f);
  float var  = ss * (1.f / 1024.f) - mean * mean;
  float rstd = rsqrtf(var + 1e-5f);

  float4 yv = reinterpret_cast<const float4*>(Y + (size_t)row * NST)[t];
  float4 v;
  v.x = yv.x + (xv.x - mean) * rstd;
  v.y = yv.y + (xv.y - mean) * rstd;
  v.z = yv.z + (xv.z - mean) * rstd;
  v.w = yv.w + (xv.w - mean) * rstd;

  s  = v.x + v.y + v.z + v.w;
  ss = v.x * v.x + v.y * v.y + v.z * v.z + v.w * v.w;
#pragma unroll
  for (int m = 1; m < 64; m <<= 1) {
    s += __shfl_xor(s, m, 64); ss += __shfl_xor(ss, m, 64);
  }
  if ((t & 63) == 0) { ps2[wv] = s; pss2[wv] = ss; }
  __syncthreads();
  s = ps2[0] + ps2[1] + ps2[2] + ps2[3];
  ss = pss2[0] + pss2[1] + pss2[2] + pss2[3];
  mean = s * (1.f / 1024.f);
  var  = ss * (1.f / 1024.f) - mean * mean;
  rstd = rsqrtf(var + 1e-5f);
  v.x = (v.x - mean) * rstd; v.y = (v.y - mean) * rstd;
  v.z = (v.z - mean) * rstd; v.w = (v.w - mean) * rstd;
  reinterpret_cast<float4*>(O + (size_t)row * NST)[t] = v;
}

// ---------------------------------------------------------------------------
// ScaleGRU scan — diagonal MFMA, gate-in-wave v3 (single chain on 32 lanes).
// Wave w owns blocks {w, w+8, w+16, w+24, w+32, w+40} = r,z,n pre-acts for
// units u1=16w+(l&15) and u2=128+16w+(l&15). Uniform-A means every D row is
// valid, so lanes 16..31 (col = l&15) are as good as 0..15: lane l<32 owns
// u = 16w+(l&15)+(l&16?128:0) and SELECTS its pre-acts via v_cndmask
// (hi?a1:a0 etc) -> ONE ~45-instr gate chain on 32 lanes (R12/R14 ran two
// sequential 16-lane chains = 4x the per-SIMD gate work of R10, eating the
// saved barrier). Single lgkm-only barrier/step, h double-buffered.
// ---------------------------------------------------------------------------
#define SCAN_BAR() asm volatile("s_waitcnt lgkmcnt(0)\n\ts_barrier" ::: "memory")

#define DECLB(i) half8 B##i##_0, B##i##_1, B##i##_2, B##i##_3, \
                       B##i##_4, B##i##_5, B##i##_6, B##i##_7;
#define LOADBn(i, nb) \
  B##i##_0 = wpB[((nb)*8+0)*64]; B##i##_1 = wpB[((nb)*8+1)*64]; \
  B##i##_2 = wpB[((nb)*8+2)*64]; B##i##_3 = wpB[((nb)*8+3)*64]; \
  B##i##_4 = wpB[((nb)*8+4)*64]; B##i##_5 = wpB[((nb)*8+5)*64]; \
  B##i##_6 = wpB[((nb)*8+6)*64]; B##i##_7 = wpB[((nb)*8+7)*64];

#define KCSTEP(kc) { \
  half8 a = hp[(kc) * 4]; \
  a0 = MFMA16(a, B0_##kc, a0); a1 = MFMA16(a, B1_##kc, a1); \
  a2 = MFMA16(a, B2_##kc, a2); a3 = MFMA16(a, B3_##kc, a3); \
  a4 = MFMA16(a, B4_##kc, a4); a5 = MFMA16(a, B5_##kc, a5); }

__global__ __attribute__((amdgpu_flat_work_group_size(512, 512)))
void scan_diag(
    const half8* __restrict__ wB,     // frag cache [3*4][384][64]
    const float* __restrict__ gbn,    // [3,4,256]
    const float* __restrict__ gls,    // [3,4]
    const float* __restrict__ igb,    // [3][C_CH,3072]
    const float* __restrict__ h0,     // [256]
    float* __restrict__ hst,          // [3*4*256] carried h state
    float* __restrict__ yb,           // [3][C_CH,1024]
    int d)
{
  const int lidx = blockIdx.x >> 2;
  const int ch   = blockIdx.x & 3;
  const int c    = d - lidx;
  if (c < 0 || c >= NCHUNK) return;

  const int j = threadIdx.x;
  const int w = j >> 6, l = j & 63;
  const int lc = lidx * 4 + ch;
  const float* igc = igb + (size_t)lidx * (C_CH * LD_IG) + ch * 768;
  float* yc        = yb + (size_t)lidx * (C_CH * NST) + ch * GHH;

  // blocks {w, w+8, w+16, w+24, w+32, w+40}: (r,u1),(r,u2),(z,u1),(z,u2),(n,u1),(n,u2)
  const half8* wpB = wB + (size_t)lc * 24576 + l;
  DECLB(0) DECLB(1) DECLB(2) DECLB(3) DECLB(4) DECLB(5)
  LOADBn(0, w)      LOADBn(1, w + 8)  LOADBn(2, w + 16)
  LOADBn(3, w + 24) LOADBn(4, w + 32) LOADBn(5, w + 40)

  __shared__ __align__(16) _Float16 hsl[2][GHH];   // double-buffered h

  const bool glane = (l < 32);
  const bool hi    = (l & 16) != 0;
  const int u = 16 * w + (l & 15) + (hi ? 128 : 0);   // valid when glane

  float ls = gls[lc];
  ls = fminf(fmaxf(ls, -10.f), 10.f);
  const float inv_s = __expf(-ls);
  float bnu = 0.f, h = 0.f, ir = 0.f, iz = 0.f, in_ = 0.f;
  if (glane) {
    h   = (c == 0) ? h0[u] : hst[lc * GHH + u];
    bnu = gbn[lc * GHH + u];
    hsl[0][u] = (_Float16)h;
    ir = igc[u]; iz = igc[256 + u]; in_ = igc[512 + u];
  }
  SCAN_BAR();

  for (int t = 0; t < C_CH; ++t) {
    float nr = 0.f, nz = 0.f, nn = 0.f;
    if (glane && t + 1 < C_CH) {
      const float* p = igc + (size_t)(t + 1) * LD_IG;
      nr = p[u]; nz = p[256 + u]; nn = p[512 + u];
    }
    const half8* hp = reinterpret_cast<const half8*>(hsl[t & 1]) + (l >> 4);
    f32x4 a0 = {0.f, 0.f, 0.f, 0.f}, a1 = a0, a2 = a0, a3 = a0, a4 = a0, a5 = a0;
    KCSTEP(0) KCSTEP(1) KCSTEP(2) KCSTEP(3)
    KCSTEP(4) KCSTEP(5) KCSTEP(6) KCSTEP(7)
    if (glane) {
      const float pr = hi ? a1[0] : a0[0];   // v_cndmask selects u's pre-acts
      const float pz = hi ? a3[0] : a2[0];
      const float pn = hi ? a5[0] : a4[0];
      const float rg = sigmoid_f(ir + pr);
      const float zg = sigmoid_f(iz + pz);
      const float ng = tanh_f(in_ + rg * (pn + bnu));
      const float hw = ng + zg * (h - ng);
      h = (hw - h) * inv_s + h;
      yc[(size_t)t * NST + u] = h;
      hsl[(t + 1) & 1][u] = (_Float16)h;
    }
    SCAN_BAR();
    ir = nr; iz = nz; in_ = nn;
  }
  if (glane) hst[lc * GHH + u] = h;
}

// ---------------------------------------------------------------------------
// Classifier second GEMM: N=10, K=1024. One block per row (unchanged).
// ---------------------------------------------------------------------------
__global__ __launch_bounds__(256) void gemv_cls(const float* __restrict__ A,
                                                const float* __restrict__ W,
                                                const float* __restrict__ b,
                                                float* __restrict__ out)
{
  const int m = blockIdx.x, t = threadIdx.x;
  float4 a = reinterpret_cast<const float4*>(A + (size_t)m * NST)[t];
  float p[10];
#pragma unroll
  for (int n = 0; n < 10; ++n) {
    float4 w = reinterpret_cast<const float4*>(W + (size_t)n * NST)[t];
    p[n] = a.x * w.x + a.y * w.y + a.z * w.z + a.w * w.w;
  }
#pragma unroll
  for (int n = 0; n < 10; ++n)
#pragma unroll
    for (int msk = 1; msk < 64; msk <<= 1) p[n] += __shfl_xor(p[n], msk, 64);
  __shared__ float red[4][10];
  const int wv = t >> 6;
  if ((t & 63) == 0) {
#pragma unroll
    for (int n = 0; n < 10; ++n) red[wv][n] = p[n];
  }
  __syncthreads();
  if (t < 10) {
    float v = red[0][t] + red[1][t] + red[2][t] + red[3][t] + b[t];
    out[(size_t)m * 10 + t] = v;
  }
}

// ---------------------------------------------------------------------------
extern "C" void kernel_launch(void* const* d_in, const int* in_sizes, int n_in,
                              void* d_out, int out_size, void* d_ws, size_t ws_size,
                              hipStream_t stream) {
  const float* inputs = (const float*)d_in[0];
  const float* h0     = (const float*)d_in[1];
  // d_in[2] = yinit_guess: unused (exact solution independent of it)
  const float* enc_w1 = (const float*)d_in[3];
  const float* enc_b1 = (const float*)d_in[4];
  const float* enc_w2 = (const float*)d_in[5];
  const float* enc_b2 = (const float*)d_in[6];
  const float* gwih   = (const float*)d_in[7];   // [3,4,768,1024]
  const float* gwhh   = (const float*)d_in[8];   // [3,4,768,256]
  const float* gb     = (const float*)d_in[9];   // [3,4,768]
  const float* gbn    = (const float*)d_in[10];  // [3,4,256]
  const float* gls    = (const float*)d_in[11];  // [3,4,1]
  const float* mw1    = (const float*)d_in[12];
  const float* mb1    = (const float*)d_in[13];
  const float* mw2    = (const float*)d_in[14];
  const float* mb2    = (const float*)d_in[15];
  const float* cw1    = (const float*)d_in[16];
  const float* cb1    = (const float*)d_in[17];
  const float* cw2    = (const float*)d_in[18];
  const float* cb2    = (const float*)d_in[19];
  float* out = (float*)d_out;

  // ws layout (bytes) — identical to R11 (tops out 162.3MB, proven)
  char* ws = (char*)d_ws;
  float* x0    = (float*)(ws);                        // [8192,1024] 33.5MB
  float* xr1   = (float*)(ws + 33554432ull);          // ring [2][C,1024] 8.4MB
  float* xr2   = (float*)(ws + 41943040ull);          // ring [2][C,1024] 8.4MB
  float* igbuf = (float*)(ws + 50331648ull);          // [3][C,3072] 37.7MB (+enc scratch)
  half8* gw16  = (half8*)(ws + 88080384ull);          // scan frag cache 4.7MB
  float* bufY  = (float*)(ws + 92798976ull);          // [3][C,1024] 12.6MB
  float* bufYn = (float*)(ws + 105381888ull);         // [C,1024] 4.2MB
  float* bufH  = (float*)(ws + 109576192ull);         // [C,1024] 4.2MB
  float* xitmp = (float*)(ws + 113770496ull);         // [C,1024] 4.2MB
  float* xf    = (float*)(ws + 117964800ull);         // [C,1024] 4.2MB
  float* clsH  = (float*)(ws + 122159104ull);         // [C,1024] 4.2MB
  float* hst   = (float*)(ws + 126353408ull);         // [3,4,256] 12KB
  _Float16* wf = (_Float16*)(ws + 126365696ull);      // f16 weights 35.9MB

  // f16 weight sub-offsets (in halfs)
  _Float16* wh_enc1 = wf;                     // 1024x128
  _Float16* wh_enc2 = wf + 131072;            // 1024x1024
  _Float16* wh_wih  = wf + 1179648;           // 3x 3072x1024
  _Float16* wh_mw1  = wf + 10616832;          // 3x 1024x1024
  _Float16* wh_mw2  = wf + 13762560;          // 3x 1024x1024
  _Float16* wh_cw1  = wf + 16908288;          // 1024x1024

  const dim3 blk(256);
  const dim3 g_enc(8192 / 64, 1024 / 64);
  const dim3 g_ig(C_CH / 64, 3072 / 64);
  const dim3 g_mlp(C_CH / 64, 1024 / 64);

  auto xptr = [&](int lth, int c) -> float* {
    if (lth == 0) return x0 + (size_t)c * C_CH * NST;
    float* base = (lth == 1) ? xr1 : xr2;
    return base + (size_t)(c & 1) * C_CH * NST;
  };

  // scan frag cache + GEMM weight conversion
  prep_whh<<<dim3(1152), blk, 0, stream>>>(gwhh, gw16);
  cvt_to_h<<<dim3(64),   blk, 0, stream>>>(enc_w1, wh_enc1, 16384);
  cvt_to_h<<<dim3(512),  blk, 0, stream>>>(enc_w2, wh_enc2, 131072);
  cvt_to_h<<<dim3(4608), blk, 0, stream>>>(gwih,   wh_wih,  1179648);
  cvt_to_h<<<dim3(1536), blk, 0, stream>>>(mw1,    wh_mw1,  393216);
  cvt_to_h<<<dim3(1536), blk, 0, stream>>>(mw2,    wh_mw2,  393216);
  cvt_to_h<<<dim3(512),  blk, 0, stream>>>(cw1,    wh_cw1,  131072);

  // encoder (full T): hidden in igbuf scratch (free until diagonal 0's pre)
  gemm_h<0, true ><<<g_enc, blk, 0, stream>>>(inputs, wh_enc1, enc_b1, nullptr,
                                              (float*)igbuf, 8192, 1024, 128, nullptr);
  gemm_h<0, false><<<g_enc, blk, 0, stream>>>((float*)igbuf, wh_enc2, enc_b2, nullptr,
                                              x0, 8192, 1024, 1024, nullptr);

  for (int d = 0; d < NDIAG; ++d) {
    // --- pre: ig(l, c) for every pair active at diagonal d ---
    for (int lth = 0; lth < 3; ++lth) {
      const int c = d - lth;
      if (c < 0 || c >= NCHUNK) continue;
      ln_kernel<false><<<dim3(C_CH), blk, 0, stream>>>(xptr(lth, c), nullptr, xitmp);
      gemm_h<1, false><<<g_ig, blk, 0, stream>>>(
          xitmp, wh_wih + (size_t)lth * 3145728, gb + (size_t)lth * 3072,
          nullptr, igbuf + (size_t)lth * C_CH * LD_IG, C_CH, 3072, 1024,
          gls + (size_t)lth * 4);
    }
    // --- scan diagonal: up to 12 (layer,channel) blocks in parallel ---
    scan_diag<<<dim3(12), dim3(512), 0, stream>>>(gw16, gbn, gls, igbuf,
                                                  h0, hst, bufY, d);
    // --- post: y -> next layer input (or classifier) per active pair ---
    for (int lth = 0; lth < 3; ++lth) {
      const int c = d - lth;
      if (c < 0 || c >= NCHUNK) continue;
      ln2_kernel<<<dim3(C_CH), blk, 0, stream>>>(
          bufY + (size_t)lth * C_CH * NST, xptr(lth, c), bufYn);
      gemm_h<0, true ><<<g_mlp, blk, 0, stream>>>(
          bufYn, wh_mw1 + (size_t)lth * 1048576, mb1 + (size_t)lth * 1024,
          nullptr, bufH, C_CH, 1024, 1024, nullptr);
      float* xnext = (lth < 2) ? xptr(lth + 1, c) : xf;
      gemm_h<2, false><<<g_mlp, blk, 0, stream>>>(
          bufH, wh_mw2 + (size_t)lth * 1048576, mb2 + (size_t)lth * 1024,
          bufYn, xnext, C_CH, 1024, 1024, nullptr);
      if (lth == 2) {   // classifier on this finished chunk
        gemm_h<0, true><<<g_mlp, blk, 0, stream>>>(
            xf, wh_cw1, cb1, nullptr, clsH, C_CH, 1024, 1024, nullptr);
        gemv_cls<<<dim3(C_CH), blk, 0, stream>>>(clsH, cw2, cb2,
                                                 out + (size_t)c * C_CH * 10);
      }
    }
  }
}

// Round 16
// 11414.243 us; speedup vs baseline: 1.4205x; 1.0550x over previous
//
#include <hip/hip_runtime.h>

// MultiScaleGRU: T=8192, NINP=128, NSTATE=1024, NCH=4, GH=256, NLAYER=3, NCLASS=10
#define T_SEQ  8192
#define NST    1024
#define GHH    256
#define LD_IG  3072      // 4 channels * 768 ig columns
#define C_CH   1024      // pipeline chunk length
#define NCHUNK 8
#define NDIAG  10        // NCHUNK + NLAYER - 1

typedef _Float16 half8 __attribute__((ext_vector_type(8)));
typedef float f32x4 __attribute__((ext_vector_type(4)));

#define MFMA16(a, b, c) __builtin_amdgcn_mfma_f32_16x16x32_f16(a, b, c, 0, 0, 0)

__device__ __forceinline__ float sigmoid_f(float x) {
  return 1.0f / (1.0f + __expf(-x));
}
__device__ __forceinline__ float tanh_f(float x) {
  float ax = fabsf(x);
  float e = __expf(-2.0f * ax);
  float t = (1.0f - e) / (1.0f + e);
  return copysignf(t, x);
}

// layer z's input chunk: layer 0 reads the persistent x0; layers 1,2 read the
// single-slot xn[z-1] (produced at post(d-1), consumed only at pre/post(d))
__device__ __forceinline__ const float* xin_ptr(const float* x0, const float* xn,
                                                int z, int c) {
  return (z == 0) ? x0 + (size_t)c * C_CH * NST
                  : xn + (size_t)(z - 1) * C_CH * NST;
}

// ---------------------------------------------------------------------------
// Prep: whh [3,4,768,256] f32 -> f16 MFMA B-fragment cache (R7/R10-verified).
// ---------------------------------------------------------------------------
__global__ __launch_bounds__(256) void prep_whh(const float* __restrict__ whh,
                                                half8* __restrict__ wB)
{
  const int idx = blockIdx.x * 256 + threadIdx.x;   // 0 .. 294911
  const int lc  = idx / 24576;                      // layer*4+ch
  const int rem = idx - lc * 24576;
  const int g_id = rem >> 6, l = rem & 63;
  const int nb = g_id >> 3, kc = g_id & 7;
  const int g = nb >> 4, ub = nb & 15;
  const int n = l & 15, kg = l >> 4;
  const int row = g * 256 + ub * 16 + n;
  const int col = kc * 32 + kg * 8;
  const float* src = whh + (size_t)lc * 196608 + (size_t)row * 256 + col;
  float4 x0 = *reinterpret_cast<const float4*>(src);
  float4 x1 = *reinterpret_cast<const float4*>(src + 4);
  half8 o;
  o[0] = (_Float16)x0.x; o[1] = (_Float16)x0.y;
  o[2] = (_Float16)x0.z; o[3] = (_Float16)x0.w;
  o[4] = (_Float16)x1.x; o[5] = (_Float16)x1.y;
  o[6] = (_Float16)x1.z; o[7] = (_Float16)x1.w;
  wB[idx] = o;
}

// ---------------------------------------------------------------------------
// Weight f32 -> f16 converter (row-major, layout-preserving). n8 = elems/8.
// ---------------------------------------------------------------------------
__global__ __launch_bounds__(256) void cvt_to_h(const float* __restrict__ src,
                                                _Float16* __restrict__ dst, int n8)
{
  const int i = blockIdx.x * 256 + threadIdx.x;
  if (i >= n8) return;
  float4 a = reinterpret_cast<const float4*>(src)[2 * i];
  float4 b = reinterpret_cast<const float4*>(src)[2 * i + 1];
  half8 o;
  o[0] = (_Float16)a.x; o[1] = (_Float16)a.y; o[2] = (_Float16)a.z; o[3] = (_Float16)a.w;
  o[4] = (_Float16)b.x; o[5] = (_Float16)b.y; o[6] = (_Float16)b.z; o[7] = (_Float16)b.w;
  reinterpret_cast<half8*>(dst)[i] = o;
}

// ---------------------------------------------------------------------------
// f16-MFMA GEMM tile body (R11-verified math): C = epi(A @ Wh^T).
// Shared by the standalone and z-batched wrappers.
// ---------------------------------------------------------------------------
template<int EPI, bool RELU>
__device__ __forceinline__ void gemm_body(
    const float* __restrict__ A, const _Float16* __restrict__ Wh,
    const float* __restrict__ bias, const float* __restrict__ R,
    float* __restrict__ C, int N, int K, const float* __restrict__ log_s,
    int bm, int bn, _Float16 (*As)[40], _Float16 (*Ws)[40])
{
  const int t = threadIdx.x;
  const int wave = t >> 6, l = t & 63;
  const int wm = (wave & 1) * 32, wn = (wave >> 1) * 32;
  const int sr = t >> 2, sc = (t & 3) * 8;
  const int fr = l & 15, fk = (l >> 4) * 8;

  f32x4 acc00 = {0.f, 0.f, 0.f, 0.f}, acc01 = acc00, acc10 = acc00, acc11 = acc00;

  const float* Ap     = A  + (size_t)(bm + sr) * K + sc;
  const _Float16* Wp  = Wh + (size_t)(bn + sr) * K + sc;

  for (int k0 = 0; k0 < K; k0 += 32) {
    float4 a0 = *reinterpret_cast<const float4*>(Ap + k0);
    float4 a1 = *reinterpret_cast<const float4*>(Ap + k0 + 4);
    half8 av;
    av[0] = (_Float16)a0.x; av[1] = (_Float16)a0.y;
    av[2] = (_Float16)a0.z; av[3] = (_Float16)a0.w;
    av[4] = (_Float16)a1.x; av[5] = (_Float16)a1.y;
    av[6] = (_Float16)a1.z; av[7] = (_Float16)a1.w;
    *reinterpret_cast<half8*>(&As[sr][sc]) = av;
    *reinterpret_cast<half8*>(&Ws[sr][sc]) =
        *reinterpret_cast<const half8*>(Wp + k0);
    __syncthreads();
    half8 af0 = *reinterpret_cast<const half8*>(&As[wm + fr][fk]);
    half8 af1 = *reinterpret_cast<const half8*>(&As[wm + 16 + fr][fk]);
    half8 bf0 = *reinterpret_cast<const half8*>(&Ws[wn + fr][fk]);
    half8 bf1 = *reinterpret_cast<const half8*>(&Ws[wn + 16 + fr][fk]);
    acc00 = MFMA16(af0, bf0, acc00);
    acc01 = MFMA16(af0, bf1, acc01);
    acc10 = MFMA16(af1, bf0, acc10);
    acc11 = MFMA16(af1, bf1, acc11);
    __syncthreads();
  }

#define EPI_STORE(ac, mi, ni) { \
    const int n_ = bn + wn + (ni) * 16 + fr; \
    const float bv = bias[n_]; \
    float sc_ = 1.f; \
    if (EPI == 1) { \
      float lsv = log_s[n_ / 768]; \
      lsv = fminf(fmaxf(lsv, -10.f), 10.f); \
      sc_ = __expf(-lsv); \
    } \
    _Pragma("unroll") \
    for (int q = 0; q < 4; ++q) { \
      const int m_ = bm + wm + (mi) * 16 + (l >> 4) * 4 + q; \
      float v = ac[q]; \
      if (EPI == 1) v *= sc_; \
      v += bv; \
      if (EPI == 2) v += R[(size_t)m_ * N + n_]; \
      if (RELU) v = fmaxf(v, 0.f); \
      C[(size_t)m_ * N + n_] = v; \
    } }
  EPI_STORE(acc00, 0, 0) EPI_STORE(acc01, 0, 1)
  EPI_STORE(acc10, 1, 0) EPI_STORE(acc11, 1, 1)
#undef EPI_STORE
}

// standalone (encoder / classifier)
template<int EPI, bool RELU>
__global__ __launch_bounds__(256) void gemm_h(
    const float* __restrict__ A, const _Float16* __restrict__ Wh,
    const float* __restrict__ bias, const float* __restrict__ R,
    float* __restrict__ C, int M, int N, int K,
    const float* __restrict__ log_s)
{
  __shared__ _Float16 As[64][40];
  __shared__ _Float16 Ws[64][40];
  gemm_body<EPI, RELU>(A, Wh, bias, R, C, N, K, log_s,
                       blockIdx.x * 64, blockIdx.y * 64, As, Ws);
}

// z-batched over layers: per-z strides; inactive (layer,chunk) pairs exit.
// For EPI==2 the out base xn has z-stride C*NST (layer z writes xn[z]).
template<int EPI, bool RELU>
__global__ __launch_bounds__(256) void gemm_b(
    const float* __restrict__ Abase, size_t Astride,
    const _Float16* __restrict__ Wbase, size_t Wstride,
    const float* __restrict__ bbase, size_t bstride,
    const float* __restrict__ Rbase, size_t Rstride,
    float* __restrict__ Cbase, size_t Cstride,
    int N, int K, const float* __restrict__ lsbase, int d)
{
  const int z = blockIdx.z;
  if ((unsigned)(d - z) >= NCHUNK) return;
  __shared__ _Float16 As[64][40];
  __shared__ _Float16 Ws[64][40];
  gemm_body<EPI, RELU>(Abase + (size_t)z * Astride, Wbase + (size_t)z * Wstride,
                       bbase + (size_t)z * bstride,
                       Rbase ? Rbase + (size_t)z * Rstride : nullptr,
                       Cbase + (size_t)z * Cstride, N, K,
                       lsbase ? lsbase + (size_t)z * 4 : nullptr,
                       blockIdx.x * 64, blockIdx.y * 64, As, Ws);
}

// ---------------------------------------------------------------------------
// Batched pre-LN: O[z] = LN(xin(z, d-z)) for active layers. grid = 3*C_CH.
// ---------------------------------------------------------------------------
__global__ __launch_bounds__(256) void ln_pre_b(const float* __restrict__ x0,
                                                const float* __restrict__ xn,
                                                float* __restrict__ O, int d)
{
  const int z = blockIdx.x >> 10, row = blockIdx.x & 1023;
  const int c = d - z;
  if ((unsigned)c >= NCHUNK) return;
  const int t = threadIdx.x;
  const float* X = xin_ptr(x0, xn, z, c) + (size_t)row * NST;
  float4 v = reinterpret_cast<const float4*>(X)[t];
  float s  = v.x + v.y + v.z + v.w;
  float ss = v.x * v.x + v.y * v.y + v.z * v.z + v.w * v.w;
#pragma unroll
  for (int m = 1; m < 64; m <<= 1) {
    s += __shfl_xor(s, m, 64); ss += __shfl_xor(ss, m, 64);
  }
  __shared__ float ps[4], pss[4];
  const int wv = t >> 6;
  if ((t & 63) == 0) { ps[wv] = s; pss[wv] = ss; }
  __syncthreads();
  s  = ps[0] + ps[1] + ps[2] + ps[3];
  ss = pss[0] + pss[1] + pss[2] + pss[3];
  const float mean = s * (1.f / 1024.f);
  const float var  = ss * (1.f / 1024.f) - mean * mean;
  const float rstd = rsqrtf(var + 1e-5f);
  v.x = (v.x - mean) * rstd; v.y = (v.y - mean) * rstd;
  v.z = (v.z - mean) * rstd; v.w = (v.w - mean) * rstd;
  reinterpret_cast<float4*>(O + ((size_t)z * C_CH + row) * NST)[t] = v;
}

// ---------------------------------------------------------------------------
// Batched fused double-LN, IN-PLACE in Y: Y[z] = LN(Y[z] + LN(xin(z,d-z))).
// Per-thread reads complete before the write to the same row -> safe.
// ---------------------------------------------------------------------------
__global__ __launch_bounds__(256) void ln2_b(float* __restrict__ Y,
                                             const float* __restrict__ x0,
                                             const float* __restrict__ xn,
                                             int d)
{
  const int z = blockIdx.x >> 10, row = blockIdx.x & 1023;
  const int c = d - z;
  if ((unsigned)c >= NCHUNK) return;
  const int t = threadIdx.x;
  const int wv = t >> 6;
  __shared__ float ps[4], pss[4], ps2[4], pss2[4];

  const float* X = xin_ptr(x0, xn, z, c) + (size_t)row * NST;
  float* Yr = Y + ((size_t)z * C_CH + row) * NST;

  float4 xv = reinterpret_cast<const float4*>(X)[t];
  float s  = xv.x + xv.y + xv.z + xv.w;
  float ss = xv.x * xv.x + xv.y * xv.y + xv.z * xv.z + xv.w * xv.w;
#pragma unroll
  for (int m = 1; m < 64; m <<= 1) {
    s += __shfl_xor(s, m, 64); ss += __shfl_xor(ss, m, 64);
  }
  if ((t & 63) == 0) { ps[wv] = s; pss[wv] = ss; }
  __syncthreads();
  s = ps[0] + ps[1] + ps[2] + ps[3];
  ss = pss[0] + pss[1] + pss[2] + pss[3];
  float mean = s * (1.f / 1024.f);
  float var  = ss * (1.f / 1024.f) - mean * mean;
  float rstd = rsqrtf(var + 1e-5f);

  float4 yv = reinterpret_cast<const float4*>(Yr)[t];
  float4 v;
  v.x = yv.x + (xv.x - mean) * rstd;
  v.y = yv.y + (xv.y - mean) * rstd;
  v.z = yv.z + (xv.z - mean) * rstd;
  v.w = yv.w + (xv.w - mean) * rstd;

  s  = v.x + v.y + v.z + v.w;
  ss = v.x * v.x + v.y * v.y + v.z * v.z + v.w * v.w;
#pragma unroll
  for (int m = 1; m < 64; m <<= 1) {
    s += __shfl_xor(s, m, 64); ss += __shfl_xor(ss, m, 64);
  }
  if ((t & 63) == 0) { ps2[wv] = s; pss2[wv] = ss; }
  __syncthreads();
  s = ps2[0] + ps2[1] + ps2[2] + ps2[3];
  ss = pss2[0] + pss2[1] + pss2[2] + pss2[3];
  mean = s * (1.f / 1024.f);
  var  = ss * (1.f / 1024.f) - mean * mean;
  rstd = rsqrtf(var + 1e-5f);
  v.x = (v.x - mean) * rstd; v.y = (v.y - mean) * rstd;
  v.z = (v.z - mean) * rstd; v.w = (v.w - mean) * rstd;
  reinterpret_cast<float4*>(Yr)[t] = v;
}

// ---------------------------------------------------------------------------
// ScaleGRU scan — diagonal MFMA, gate-in-wave v3 (UNCHANGED from R15,
// verified: 1.019ms/dispatch, absmax 0.0625).
// ---------------------------------------------------------------------------
#define SCAN_BAR() asm volatile("s_waitcnt lgkmcnt(0)\n\ts_barrier" ::: "memory")

#define DECLB(i) half8 B##i##_0, B##i##_1, B##i##_2, B##i##_3, \
                       B##i##_4, B##i##_5, B##i##_6, B##i##_7;
#define LOADBn(i, nb) \
  B##i##_0 = wpB[((nb)*8+0)*64]; B##i##_1 = wpB[((nb)*8+1)*64]; \
  B##i##_2 = wpB[((nb)*8+2)*64]; B##i##_3 = wpB[((nb)*8+3)*64]; \
  B##i##_4 = wpB[((nb)*8+4)*64]; B##i##_5 = wpB[((nb)*8+5)*64]; \
  B##i##_6 = wpB[((nb)*8+6)*64]; B##i##_7 = wpB[((nb)*8+7)*64];

#define KCSTEP(kc) { \
  half8 a = hp[(kc) * 4]; \
  a0 = MFMA16(a, B0_##kc, a0); a1 = MFMA16(a, B1_##kc, a1); \
  a2 = MFMA16(a, B2_##kc, a2); a3 = MFMA16(a, B3_##kc, a3); \
  a4 = MFMA16(a, B4_##kc, a4); a5 = MFMA16(a, B5_##kc, a5); }

__global__ __attribute__((amdgpu_flat_work_group_size(512, 512)))
void scan_diag(
    const half8* __restrict__ wB,     // frag cache [3*4][384][64]
    const float* __restrict__ gbn,    // [3,4,256]
    const float* __restrict__ gls,    // [3,4]
    const float* __restrict__ igb,    // [3][C_CH,3072]
    const float* __restrict__ h0,     // [256]
    float* __restrict__ hst,          // [3*4*256] carried h state
    float* __restrict__ yb,           // [3][C_CH,1024]
    int d)
{
  const int lidx = blockIdx.x >> 2;
  const int ch   = blockIdx.x & 3;
  const int c    = d - lidx;
  if (c < 0 || c >= NCHUNK) return;

  const int j = threadIdx.x;
  const int w = j >> 6, l = j & 63;
  const int lc = lidx * 4 + ch;
  const float* igc = igb + (size_t)lidx * (C_CH * LD_IG) + ch * 768;
  float* yc        = yb + (size_t)lidx * (C_CH * NST) + ch * GHH;

  const half8* wpB = wB + (size_t)lc * 24576 + l;
  DECLB(0) DECLB(1) DECLB(2) DECLB(3) DECLB(4) DECLB(5)
  LOADBn(0, w)      LOADBn(1, w + 8)  LOADBn(2, w + 16)
  LOADBn(3, w + 24) LOADBn(4, w + 32) LOADBn(5, w + 40)

  __shared__ __align__(16) _Float16 hsl[2][GHH];   // double-buffered h

  const bool glane = (l < 32);
  const bool hi    = (l & 16) != 0;
  const int u = 16 * w + (l & 15) + (hi ? 128 : 0);

  float ls = gls[lc];
  ls = fminf(fmaxf(ls, -10.f), 10.f);
  const float inv_s = __expf(-ls);
  float bnu = 0.f, h = 0.f, ir = 0.f, iz = 0.f, in_ = 0.f;
  if (glane) {
    h   = (c == 0) ? h0[u] : hst[lc * GHH + u];
    bnu = gbn[lc * GHH + u];
    hsl[0][u] = (_Float16)h;
    ir = igc[u]; iz = igc[256 + u]; in_ = igc[512 + u];
  }
  SCAN_BAR();

  for (int t = 0; t < C_CH; ++t) {
    float nr = 0.f, nz = 0.f, nn = 0.f;
    if (glane && t + 1 < C_CH) {
      const float* p = igc + (size_t)(t + 1) * LD_IG;
      nr = p[u]; nz = p[256 + u]; nn = p[512 + u];
    }
    const half8* hp = reinterpret_cast<const half8*>(hsl[t & 1]) + (l >> 4);
    f32x4 a0 = {0.f, 0.f, 0.f, 0.f}, a1 = a0, a2 = a0, a3 = a0, a4 = a0, a5 = a0;
    KCSTEP(0) KCSTEP(1) KCSTEP(2) KCSTEP(3)
    KCSTEP(4) KCSTEP(5) KCSTEP(6) KCSTEP(7)
    if (glane) {
      const float pr = hi ? a1[0] : a0[0];
      const float pz = hi ? a3[0] : a2[0];
      const float pn = hi ? a5[0] : a4[0];
      const float rg = sigmoid_f(ir + pr);
      const float zg = sigmoid_f(iz + pz);
      const float ng = tanh_f(in_ + rg * (pn + bnu));
      const float hw = ng + zg * (h - ng);
      h = (hw - h) * inv_s + h;
      yc[(size_t)t * NST + u] = h;
      hsl[(t + 1) & 1][u] = (_Float16)h;
    }
    SCAN_BAR();
    ir = nr; iz = nz; in_ = nn;
  }
  if (glane) hst[lc * GHH + u] = h;
}

// ---------------------------------------------------------------------------
// Classifier second GEMM: N=10, K=1024. One block per row (unchanged).
// ---------------------------------------------------------------------------
__global__ __launch_bounds__(256) void gemv_cls(const float* __restrict__ A,
                                                const float* __restrict__ W,
                                                const float* __restrict__ b,
                                                float* __restrict__ out)
{
  const int m = blockIdx.x, t = threadIdx.x;
  float4 a = reinterpret_cast<const float4*>(A + (size_t)m * NST)[t];
  float p[10];
#pragma unroll
  for (int n = 0; n < 10; ++n) {
    float4 w = reinterpret_cast<const float4*>(W + (size_t)n * NST)[t];
    p[n] = a.x * w.x + a.y * w.y + a.z * w.z + a.w * w.w;
  }
#pragma unroll
  for (int n = 0; n < 10; ++n)
#pragma unroll
    for (int msk = 1; msk < 64; msk <<= 1) p[n] += __shfl_xor(p[n], msk, 64);
  __shared__ float red[4][10];
  const int wv = t >> 6;
  if ((t & 63) == 0) {
#pragma unroll
    for (int n = 0; n < 10; ++n) red[wv][n] = p[n];
  }
  __syncthreads();
  if (t < 10) {
    float v = red[0][t] + red[1][t] + red[2][t] + red[3][t] + b[t];
    out[(size_t)m * 10 + t] = v;
  }
}

// ---------------------------------------------------------------------------
extern "C" void kernel_launch(void* const* d_in, const int* in_sizes, int n_in,
                              void* d_out, int out_size, void* d_ws, size_t ws_size,
                              hipStream_t stream) {
  const float* inputs = (const float*)d_in[0];
  const float* h0     = (const float*)d_in[1];
  // d_in[2] = yinit_guess: unused (exact solution independent of it)
  const float* enc_w1 = (const float*)d_in[3];
  const float* enc_b1 = (const float*)d_in[4];
  const float* enc_w2 = (const float*)d_in[5];
  const float* enc_b2 = (const float*)d_in[6];
  const float* gwih   = (const float*)d_in[7];   // [3,4,768,1024]
  const float* gwhh   = (const float*)d_in[8];   // [3,4,768,256]
  const float* gb     = (const float*)d_in[9];   // [3,4,768]
  const float* gbn    = (const float*)d_in[10];  // [3,4,256]
  const float* gls    = (const float*)d_in[11];  // [3,4,1]
  const float* mw1    = (const float*)d_in[12];
  const float* mb1    = (const float*)d_in[13];
  const float* mw2    = (const float*)d_in[14];
  const float* mb2    = (const float*)d_in[15];
  const float* cw1    = (const float*)d_in[16];
  const float* cb1    = (const float*)d_in[17];
  const float* cw2    = (const float*)d_in[18];
  const float* cb2    = (const float*)d_in[19];
  float* out = (float*)d_out;

  // ws layout (bytes) — tops out at 162.3MB (same as R11/R15, proven)
  char* ws = (char*)d_ws;
  float* x0    = (float*)(ws);                        // [8192,1024] 33.5MB
  float* xn    = (float*)(ws + 33554432ull);          // [3][C,1024] 12.6MB
  float* xitmp = (float*)(ws + 46137344ull);          // [3][C,1024] 12.6MB
  float* clsH  = xitmp;                               // overlay (disjoint lifetime)
  float* igbuf = (float*)(ws + 58720256ull);          // [3][C,3072] 37.7MB
  half8* gw16  = (half8*)(ws + 96468992ull);          // scan frag cache 4.7MB
  float* bufY  = (float*)(ws + 101187584ull);         // [3][C,1024] 12.6MB
  float* bufH  = (float*)(ws + 113770496ull);         // [3][C,1024] 12.6MB
  float* hst   = (float*)(ws + 126353408ull);         // [3,4,256] 12KB
  _Float16* wf = (_Float16*)(ws + 126365696ull);      // f16 weights 35.9MB

  // f16 weight sub-offsets (in halfs)
  _Float16* wh_enc1 = wf;                     // 1024x128
  _Float16* wh_enc2 = wf + 131072;            // 1024x1024
  _Float16* wh_wih  = wf + 1179648;           // 3x 3072x1024
  _Float16* wh_mw1  = wf + 10616832;          // 3x 1024x1024
  _Float16* wh_mw2  = wf + 13762560;          // 3x 1024x1024
  _Float16* wh_cw1  = wf + 16908288;          // 1024x1024

  const dim3 blk(256);
  const dim3 g_enc(8192 / 64, 1024 / 64);
  const dim3 g_ig_b(C_CH / 64, 3072 / 64, 3);
  const dim3 g_mlp_b(C_CH / 64, 1024 / 64, 3);
  const dim3 g_mlp(C_CH / 64, 1024 / 64);

  // scan frag cache + GEMM weight conversion
  prep_whh<<<dim3(1152), blk, 0, stream>>>(gwhh, gw16);
  cvt_to_h<<<dim3(64),   blk, 0, stream>>>(enc_w1, wh_enc1, 16384);
  cvt_to_h<<<dim3(512),  blk, 0, stream>>>(enc_w2, wh_enc2, 131072);
  cvt_to_h<<<dim3(4608), blk, 0, stream>>>(gwih,   wh_wih,  1179648);
  cvt_to_h<<<dim3(1536), blk, 0, stream>>>(mw1,    wh_mw1,  393216);
  cvt_to_h<<<dim3(1536), blk, 0, stream>>>(mw2,    wh_mw2,  393216);
  cvt_to_h<<<dim3(512),  blk, 0, stream>>>(cw1,    wh_cw1,  131072);

  // encoder (full T): hidden staged in igbuf scratch (free until diagonal 0)
  gemm_h<0, true ><<<g_enc, blk, 0, stream>>>(inputs, wh_enc1, enc_b1, nullptr,
                                              (float*)igbuf, 8192, 1024, 128, nullptr);
  gemm_h<0, false><<<g_enc, blk, 0, stream>>>((float*)igbuf, wh_enc2, enc_b2, nullptr,
                                              x0, 8192, 1024, 1024, nullptr);

  for (int d = 0; d < NDIAG; ++d) {
    // --- pre (batched over layers): xi = LN(x) ; ig = (xi@wih^T)/s + b ---
    ln_pre_b<<<dim3(3 * C_CH), blk, 0, stream>>>(x0, xn, xitmp, d);
    gemm_b<1, false><<<g_ig_b, blk, 0, stream>>>(
        xitmp, (size_t)C_CH * NST, wh_wih, 3145728ull, gb, 3072ull,
        nullptr, 0ull, igbuf, (size_t)C_CH * LD_IG, 3072, 1024, gls, d);
    // --- scan diagonal: up to 12 (layer,channel) blocks in parallel ---
    scan_diag<<<dim3(12), dim3(512), 0, stream>>>(gw16, gbn, gls, igbuf,
                                                  h0, hst, bufY, d);
    // --- post (batched): y = LN(y+xi) in-place; x_next = mlp(y) + y -> xn ---
    ln2_b<<<dim3(3 * C_CH), blk, 0, stream>>>(bufY, x0, xn, d);
    gemm_b<0, true ><<<g_mlp_b, blk, 0, stream>>>(
        bufY, (size_t)C_CH * NST, wh_mw1, 1048576ull, mb1, 1024ull,
        nullptr, 0ull, bufH, (size_t)C_CH * NST, 1024, 1024, nullptr, d);
    gemm_b<2, false><<<g_mlp_b, blk, 0, stream>>>(
        bufH, (size_t)C_CH * NST, wh_mw2, 1048576ull, mb2, 1024ull,
        bufY, (size_t)C_CH * NST, xn, (size_t)C_CH * NST, 1024, 1024, nullptr, d);
    // --- classifier on layer 2's finished chunk ---
    const int c2 = d - 2;
    if (0 <= c2 && c2 < NCHUNK) {
      gemm_h<0, true><<<g_mlp, blk, 0, stream>>>(
          xn + 2ull * C_CH * NST, wh_cw1, cb1, nullptr, clsH, C_CH, 1024, 1024, nullptr);
      gemv_cls<<<dim3(C_CH), blk, 0, stream>>>(clsH, cw2, cb2,
                                               out + (size_t)c2 * C_CH * 10);
    }
  }
}

// Round 17
// 11035.109 us; speedup vs baseline: 1.4693x; 1.0344x over previous
//
#include <hip/hip_runtime.h>

// MultiScaleGRU: T=8192, NINP=128, NSTATE=1024, NCH=4, GH=256, NLAYER=3, NCLASS=10
#define T_SEQ  8192
#define NST    1024
#define GHH    256
#define LD_IG  3072      // 4 channels * 768 ig columns
#define C_CH   512       // pipeline chunk length (viable now that per-diagonal
                         // stacks are BATCHED: R14's C=512 failure was 15
                         // unbatched dispatches/diag; R16 cut that to 6)
#define NCHUNK 16
#define NDIAG  18        // NCHUNK + NLAYER - 1

typedef _Float16 half8 __attribute__((ext_vector_type(8)));
typedef float f32x4 __attribute__((ext_vector_type(4)));

#define MFMA16(a, b, c) __builtin_amdgcn_mfma_f32_16x16x32_f16(a, b, c, 0, 0, 0)

__device__ __forceinline__ float sigmoid_f(float x) {
  return 1.0f / (1.0f + __expf(-x));
}
__device__ __forceinline__ float tanh_f(float x) {
  float ax = fabsf(x);
  float e = __expf(-2.0f * ax);
  float t = (1.0f - e) / (1.0f + e);
  return copysignf(t, x);
}

// layer z's input chunk: layer 0 reads the persistent x0; layers 1,2 read the
// single-slot xn[z-1] (produced at post(d-1), consumed only at pre/post(d))
__device__ __forceinline__ const float* xin_ptr(const float* x0, const float* xn,
                                                int z, int c) {
  return (z == 0) ? x0 + (size_t)c * C_CH * NST
                  : xn + (size_t)(z - 1) * C_CH * NST;
}

// ---------------------------------------------------------------------------
// Prep: whh [3,4,768,256] f32 -> f16 MFMA B-fragment cache (R7/R10-verified).
// ---------------------------------------------------------------------------
__global__ __launch_bounds__(256) void prep_whh(const float* __restrict__ whh,
                                                half8* __restrict__ wB)
{
  const int idx = blockIdx.x * 256 + threadIdx.x;   // 0 .. 294911
  const int lc  = idx / 24576;                      // layer*4+ch
  const int rem = idx - lc * 24576;
  const int g_id = rem >> 6, l = rem & 63;
  const int nb = g_id >> 3, kc = g_id & 7;
  const int g = nb >> 4, ub = nb & 15;
  const int n = l & 15, kg = l >> 4;
  const int row = g * 256 + ub * 16 + n;
  const int col = kc * 32 + kg * 8;
  const float* src = whh + (size_t)lc * 196608 + (size_t)row * 256 + col;
  float4 x0 = *reinterpret_cast<const float4*>(src);
  float4 x1 = *reinterpret_cast<const float4*>(src + 4);
  half8 o;
  o[0] = (_Float16)x0.x; o[1] = (_Float16)x0.y;
  o[2] = (_Float16)x0.z; o[3] = (_Float16)x0.w;
  o[4] = (_Float16)x1.x; o[5] = (_Float16)x1.y;
  o[6] = (_Float16)x1.z; o[7] = (_Float16)x1.w;
  wB[idx] = o;
}

// ---------------------------------------------------------------------------
// Weight f32 -> f16 converter (row-major, layout-preserving). n8 = elems/8.
// ---------------------------------------------------------------------------
__global__ __launch_bounds__(256) void cvt_to_h(const float* __restrict__ src,
                                                _Float16* __restrict__ dst, int n8)
{
  const int i = blockIdx.x * 256 + threadIdx.x;
  if (i >= n8) return;
  float4 a = reinterpret_cast<const float4*>(src)[2 * i];
  float4 b = reinterpret_cast<const float4*>(src)[2 * i + 1];
  half8 o;
  o[0] = (_Float16)a.x; o[1] = (_Float16)a.y; o[2] = (_Float16)a.z; o[3] = (_Float16)a.w;
  o[4] = (_Float16)b.x; o[5] = (_Float16)b.y; o[6] = (_Float16)b.z; o[7] = (_Float16)b.w;
  reinterpret_cast<half8*>(dst)[i] = o;
}

// ---------------------------------------------------------------------------
// f16-MFMA GEMM tile body (R11-verified math): C = epi(A @ Wh^T).
// ---------------------------------------------------------------------------
template<int EPI, bool RELU>
__device__ __forceinline__ void gemm_body(
    const float* __restrict__ A, const _Float16* __restrict__ Wh,
    const float* __restrict__ bias, const float* __restrict__ R,
    float* __restrict__ C, int N, int K, const float* __restrict__ log_s,
    int bm, int bn, _Float16 (*As)[40], _Float16 (*Ws)[40])
{
  const int t = threadIdx.x;
  const int wave = t >> 6, l = t & 63;
  const int wm = (wave & 1) * 32, wn = (wave >> 1) * 32;
  const int sr = t >> 2, sc = (t & 3) * 8;
  const int fr = l & 15, fk = (l >> 4) * 8;

  f32x4 acc00 = {0.f, 0.f, 0.f, 0.f}, acc01 = acc00, acc10 = acc00, acc11 = acc00;

  const float* Ap     = A  + (size_t)(bm + sr) * K + sc;
  const _Float16* Wp  = Wh + (size_t)(bn + sr) * K + sc;

  for (int k0 = 0; k0 < K; k0 += 32) {
    float4 a0 = *reinterpret_cast<const float4*>(Ap + k0);
    float4 a1 = *reinterpret_cast<const float4*>(Ap + k0 + 4);
    half8 av;
    av[0] = (_Float16)a0.x; av[1] = (_Float16)a0.y;
    av[2] = (_Float16)a0.z; av[3] = (_Float16)a0.w;
    av[4] = (_Float16)a1.x; av[5] = (_Float16)a1.y;
    av[6] = (_Float16)a1.z; av[7] = (_Float16)a1.w;
    *reinterpret_cast<half8*>(&As[sr][sc]) = av;
    *reinterpret_cast<half8*>(&Ws[sr][sc]) =
        *reinterpret_cast<const half8*>(Wp + k0);
    __syncthreads();
    half8 af0 = *reinterpret_cast<const half8*>(&As[wm + fr][fk]);
    half8 af1 = *reinterpret_cast<const half8*>(&As[wm + 16 + fr][fk]);
    half8 bf0 = *reinterpret_cast<const half8*>(&Ws[wn + fr][fk]);
    half8 bf1 = *reinterpret_cast<const half8*>(&Ws[wn + 16 + fr][fk]);
    acc00 = MFMA16(af0, bf0, acc00);
    acc01 = MFMA16(af0, bf1, acc01);
    acc10 = MFMA16(af1, bf0, acc10);
    acc11 = MFMA16(af1, bf1, acc11);
    __syncthreads();
  }

#define EPI_STORE(ac, mi, ni) { \
    const int n_ = bn + wn + (ni) * 16 + fr; \
    const float bv = bias[n_]; \
    float sc_ = 1.f; \
    if (EPI == 1) { \
      float lsv = log_s[n_ / 768]; \
      lsv = fminf(fmaxf(lsv, -10.f), 10.f); \
      sc_ = __expf(-lsv); \
    } \
    _Pragma("unroll") \
    for (int q = 0; q < 4; ++q) { \
      const int m_ = bm + wm + (mi) * 16 + (l >> 4) * 4 + q; \
      float v = ac[q]; \
      if (EPI == 1) v *= sc_; \
      v += bv; \
      if (EPI == 2) v += R[(size_t)m_ * N + n_]; \
      if (RELU) v = fmaxf(v, 0.f); \
      C[(size_t)m_ * N + n_] = v; \
    } }
  EPI_STORE(acc00, 0, 0) EPI_STORE(acc01, 0, 1)
  EPI_STORE(acc10, 1, 0) EPI_STORE(acc11, 1, 1)
#undef EPI_STORE
}

// standalone (encoder / classifier)
template<int EPI, bool RELU>
__global__ __launch_bounds__(256) void gemm_h(
    const float* __restrict__ A, const _Float16* __restrict__ Wh,
    const float* __restrict__ bias, const float* __restrict__ R,
    float* __restrict__ C, int M, int N, int K,
    const float* __restrict__ log_s)
{
  __shared__ _Float16 As[64][40];
  __shared__ _Float16 Ws[64][40];
  gemm_body<EPI, RELU>(A, Wh, bias, R, C, N, K, log_s,
                       blockIdx.x * 64, blockIdx.y * 64, As, Ws);
}

// z-batched over layers: per-z strides; inactive (layer,chunk) pairs exit.
template<int EPI, bool RELU>
__global__ __launch_bounds__(256) void gemm_b(
    const float* __restrict__ Abase, size_t Astride,
    const _Float16* __restrict__ Wbase, size_t Wstride,
    const float* __restrict__ bbase, size_t bstride,
    const float* __restrict__ Rbase, size_t Rstride,
    float* __restrict__ Cbase, size_t Cstride,
    int N, int K, const float* __restrict__ lsbase, int d)
{
  const int z = blockIdx.z;
  if ((unsigned)(d - z) >= NCHUNK) return;
  __shared__ _Float16 As[64][40];
  __shared__ _Float16 Ws[64][40];
  gemm_body<EPI, RELU>(Abase + (size_t)z * Astride, Wbase + (size_t)z * Wstride,
                       bbase + (size_t)z * bstride,
                       Rbase ? Rbase + (size_t)z * Rstride : nullptr,
                       Cbase + (size_t)z * Cstride, N, K,
                       lsbase ? lsbase + (size_t)z * 4 : nullptr,
                       blockIdx.x * 64, blockIdx.y * 64, As, Ws);
}

// ---------------------------------------------------------------------------
// Batched pre-LN: O[z] = LN(xin(z, d-z)) for active layers. grid = 3*C_CH.
// ---------------------------------------------------------------------------
__global__ __launch_bounds__(256) void ln_pre_b(const float* __restrict__ x0,
                                                const float* __restrict__ xn,
                                                float* __restrict__ O, int d)
{
  const int z = blockIdx.x >> 9, row = blockIdx.x & 511;
  const int c = d - z;
  if ((unsigned)c >= NCHUNK) return;
  const int t = threadIdx.x;
  const float* X = xin_ptr(x0, xn, z, c) + (size_t)row * NST;
  float4 v = reinterpret_cast<const float4*>(X)[t];
  float s  = v.x + v.y + v.z + v.w;
  float ss = v.x * v.x + v.y * v.y + v.z * v.z + v.w * v.w;
#pragma unroll
  for (int m = 1; m < 64; m <<= 1) {
    s += __shfl_xor(s, m, 64); ss += __shfl_xor(ss, m, 64);
  }
  __shared__ float ps[4], pss[4];
  const int wv = t >> 6;
  if ((t & 63) == 0) { ps[wv] = s; pss[wv] = ss; }
  __syncthreads();
  s  = ps[0] + ps[1] + ps[2] + ps[3];
  ss = pss[0] + pss[1] + pss[2] + pss[3];
  const float mean = s * (1.f / 1024.f);
  const float var  = ss * (1.f / 1024.f) - mean * mean;
  const float rstd = rsqrtf(var + 1e-5f);
  v.x = (v.x - mean) * rstd; v.y = (v.y - mean) * rstd;
  v.z = (v.z - mean) * rstd; v.w = (v.w - mean) * rstd;
  reinterpret_cast<float4*>(O + ((size_t)z * C_CH + row) * NST)[t] = v;
}

// ---------------------------------------------------------------------------
// Batched fused double-LN, IN-PLACE in Y: Y[z] = LN(Y[z] + LN(xin(z,d-z))).
// ---------------------------------------------------------------------------
__global__ __launch_bounds__(256) void ln2_b(float* __restrict__ Y,
                                             const float* __restrict__ x0,
                                             const float* __restrict__ xn,
                                             int d)
{
  const int z = blockIdx.x >> 9, row = blockIdx.x & 511;
  const int c = d - z;
  if ((unsigned)c >= NCHUNK) return;
  const int t = threadIdx.x;
  const int wv = t >> 6;
  __shared__ float ps[4], pss[4], ps2[4], pss2[4];

  const float* X = xin_ptr(x0, xn, z, c) + (size_t)row * NST;
  float* Yr = Y + ((size_t)z * C_CH + row) * NST;

  float4 xv = reinterpret_cast<const float4*>(X)[t];
  float s  = xv.x + xv.y + xv.z + xv.w;
  float ss = xv.x * xv.x + xv.y * xv.y + xv.z * xv.z + xv.w * xv.w;
#pragma unroll
  for (int m = 1; m < 64; m <<= 1) {
    s += __shfl_xor(s, m, 64); ss += __shfl_xor(ss, m, 64);
  }
  if ((t & 63) == 0) { ps[wv] = s; pss[wv] = ss; }
  __syncthreads();
  s = ps[0] + ps[1] + ps[2] + ps[3];
  ss = pss[0] + pss[1] + pss[2] + pss[3];
  float mean = s * (1.f / 1024.f);
  float var  = ss * (1.f / 1024.f) - mean * mean;
  float rstd = rsqrtf(var + 1e-5f);

  float4 yv = reinterpret_cast<const float4*>(Yr)[t];
  float4 v;
  v.x = yv.x + (xv.x - mean) * rstd;
  v.y = yv.y + (xv.y - mean) * rstd;
  v.z = yv.z + (xv.z - mean) * rstd;
  v.w = yv.w + (xv.w - mean) * rstd;

  s  = v.x + v.y + v.z + v.w;
  ss = v.x * v.x + v.y * v.y + v.z * v.z + v.w * v.w;
#pragma unroll
  for (int m = 1; m < 64; m <<= 1) {
    s += __shfl_xor(s, m, 64); ss += __shfl_xor(ss, m, 64);
  }
  if ((t & 63) == 0) { ps2[wv] = s; pss2[wv] = ss; }
  __syncthreads();
  s = ps2[0] + ps2[1] + ps2[2] + ps2[3];
  ss = pss2[0] + pss2[1] + pss2[2] + pss2[3];
  mean = s * (1.f / 1024.f);
  var  = ss * (1.f / 1024.f) - mean * mean;
  rstd = rsqrtf(var + 1e-5f);
  v.x = (v.x - mean) * rstd; v.y = (v.y - mean) * rstd;
  v.z = (v.z - mean) * rstd; v.w = (v.w - mean) * rstd;
  reinterpret_cast<float4*>(Yr)[t] = v;
}

// ---------------------------------------------------------------------------
// ScaleGRU scan — diagonal MFMA, gate-in-wave v3 (UNCHANGED from R15/R16,
// verified: 2390 cy/step, absmax 0.0625). Loop bound now C_CH=512.
// ---------------------------------------------------------------------------
#define SCAN_BAR() asm volatile("s_waitcnt lgkmcnt(0)\n\ts_barrier" ::: "memory")

#define DECLB(i) half8 B##i##_0, B##i##_1, B##i##_2, B##i##_3, \
                       B##i##_4, B##i##_5, B##i##_6, B##i##_7;
#define LOADBn(i, nb) \
  B##i##_0 = wpB[((nb)*8+0)*64]; B##i##_1 = wpB[((nb)*8+1)*64]; \
  B##i##_2 = wpB[((nb)*8+2)*64]; B##i##_3 = wpB[((nb)*8+3)*64]; \
  B##i##_4 = wpB[((nb)*8+4)*64]; B##i##_5 = wpB[((nb)*8+5)*64]; \
  B##i##_6 = wpB[((nb)*8+6)*64]; B##i##_7 = wpB[((nb)*8+7)*64];

#define KCSTEP(kc) { \
  half8 a = hp[(kc) * 4]; \
  a0 = MFMA16(a, B0_##kc, a0); a1 = MFMA16(a, B1_##kc, a1); \
  a2 = MFMA16(a, B2_##kc, a2); a3 = MFMA16(a, B3_##kc, a3); \
  a4 = MFMA16(a, B4_##kc, a4); a5 = MFMA16(a, B5_##kc, a5); }

__global__ __attribute__((amdgpu_flat_work_group_size(512, 512)))
void scan_diag(
    const half8* __restrict__ wB,     // frag cache [3*4][384][64]
    const float* __restrict__ gbn,    // [3,4,256]
    const float* __restrict__ gls,    // [3,4]
    const float* __restrict__ igb,    // [3][C_CH,3072]
    const float* __restrict__ h0,     // [256]
    float* __restrict__ hst,          // [3*4*256] carried h state
    float* __restrict__ yb,           // [3][C_CH,1024]
    int d)
{
  const int lidx = blockIdx.x >> 2;
  const int ch   = blockIdx.x & 3;
  const int c    = d - lidx;
  if (c < 0 || c >= NCHUNK) return;

  const int j = threadIdx.x;
  const int w = j >> 6, l = j & 63;
  const int lc = lidx * 4 + ch;
  const float* igc = igb + (size_t)lidx * (C_CH * LD_IG) + ch * 768;
  float* yc        = yb + (size_t)lidx * (C_CH * NST) + ch * GHH;

  const half8* wpB = wB + (size_t)lc * 24576 + l;
  DECLB(0) DECLB(1) DECLB(2) DECLB(3) DECLB(4) DECLB(5)
  LOADBn(0, w)      LOADBn(1, w + 8)  LOADBn(2, w + 16)
  LOADBn(3, w + 24) LOADBn(4, w + 32) LOADBn(5, w + 40)

  __shared__ __align__(16) _Float16 hsl[2][GHH];   // double-buffered h

  const bool glane = (l < 32);
  const bool hi    = (l & 16) != 0;
  const int u = 16 * w + (l & 15) + (hi ? 128 : 0);

  float ls = gls[lc];
  ls = fminf(fmaxf(ls, -10.f), 10.f);
  const float inv_s = __expf(-ls);
  float bnu = 0.f, h = 0.f, ir = 0.f, iz = 0.f, in_ = 0.f;
  if (glane) {
    h   = (c == 0) ? h0[u] : hst[lc * GHH + u];
    bnu = gbn[lc * GHH + u];
    hsl[0][u] = (_Float16)h;
    ir = igc[u]; iz = igc[256 + u]; in_ = igc[512 + u];
  }
  SCAN_BAR();

  for (int t = 0; t < C_CH; ++t) {
    float nr = 0.f, nz = 0.f, nn = 0.f;
    if (glane && t + 1 < C_CH) {
      const float* p = igc + (size_t)(t + 1) * LD_IG;
      nr = p[u]; nz = p[256 + u]; nn = p[512 + u];
    }
    const half8* hp = reinterpret_cast<const half8*>(hsl[t & 1]) + (l >> 4);
    f32x4 a0 = {0.f, 0.f, 0.f, 0.f}, a1 = a0, a2 = a0, a3 = a0, a4 = a0, a5 = a0;
    KCSTEP(0) KCSTEP(1) KCSTEP(2) KCSTEP(3)
    KCSTEP(4) KCSTEP(5) KCSTEP(6) KCSTEP(7)
    if (glane) {
      const float pr = hi ? a1[0] : a0[0];
      const float pz = hi ? a3[0] : a2[0];
      const float pn = hi ? a5[0] : a4[0];
      const float rg = sigmoid_f(ir + pr);
      const float zg = sigmoid_f(iz + pz);
      const float ng = tanh_f(in_ + rg * (pn + bnu));
      const float hw = ng + zg * (h - ng);
      h = (hw - h) * inv_s + h;
      yc[(size_t)t * NST + u] = h;
      hsl[(t + 1) & 1][u] = (_Float16)h;
    }
    SCAN_BAR();
    ir = nr; iz = nz; in_ = nn;
  }
  if (glane) hst[lc * GHH + u] = h;
}

// ---------------------------------------------------------------------------
// Classifier second GEMM: N=10, K=1024. One block per row (unchanged).
// ---------------------------------------------------------------------------
__global__ __launch_bounds__(256) void gemv_cls(const float* __restrict__ A,
                                                const float* __restrict__ W,
                                                const float* __restrict__ b,
                                                float* __restrict__ out)
{
  const int m = blockIdx.x, t = threadIdx.x;
  float4 a = reinterpret_cast<const float4*>(A + (size_t)m * NST)[t];
  float p[10];
#pragma unroll
  for (int n = 0; n < 10; ++n) {
    float4 w = reinterpret_cast<const float4*>(W + (size_t)n * NST)[t];
    p[n] = a.x * w.x + a.y * w.y + a.z * w.z + a.w * w.w;
  }
#pragma unroll
  for (int n = 0; n < 10; ++n)
#pragma unroll
    for (int msk = 1; msk < 64; msk <<= 1) p[n] += __shfl_xor(p[n], msk, 64);
  __shared__ float red[4][10];
  const int wv = t >> 6;
  if ((t & 63) == 0) {
#pragma unroll
    for (int n = 0; n < 10; ++n) red[wv][n] = p[n];
  }
  __syncthreads();
  if (t < 10) {
    float v = red[0][t] + red[1][t] + red[2][t] + red[3][t] + b[t];
    out[(size_t)m * 10 + t] = v;
  }
}

// ---------------------------------------------------------------------------
extern "C" void kernel_launch(void* const* d_in, const int* in_sizes, int n_in,
                              void* d_out, int out_size, void* d_ws, size_t ws_size,
                              hipStream_t stream) {
  const float* inputs = (const float*)d_in[0];
  const float* h0     = (const float*)d_in[1];
  // d_in[2] = yinit_guess: unused (exact solution independent of it)
  const float* enc_w1 = (const float*)d_in[3];
  const float* enc_b1 = (const float*)d_in[4];
  const float* enc_w2 = (const float*)d_in[5];
  const float* enc_b2 = (const float*)d_in[6];
  const float* gwih   = (const float*)d_in[7];   // [3,4,768,1024]
  const float* gwhh   = (const float*)d_in[8];   // [3,4,768,256]
  const float* gb     = (const float*)d_in[9];   // [3,4,768]
  const float* gbn    = (const float*)d_in[10];  // [3,4,256]
  const float* gls    = (const float*)d_in[11];  // [3,4,1]
  const float* mw1    = (const float*)d_in[12];
  const float* mb1    = (const float*)d_in[13];
  const float* mw2    = (const float*)d_in[14];
  const float* mb2    = (const float*)d_in[15];
  const float* cw1    = (const float*)d_in[16];
  const float* cb1    = (const float*)d_in[17];
  const float* cw2    = (const float*)d_in[18];
  const float* cb2    = (const float*)d_in[19];
  float* out = (float*)d_out;

  // ws layout (bytes) — tops out at 151.8MB (< 162.3MB proven)
  char* ws = (char*)d_ws;
  float* x0    = (float*)(ws);                        // [8192,1024] 33.5MB
  float* xn    = (float*)(ws + 33554432ull);          // [3][C,1024] 6.3MB
  float* xitmp = (float*)(ws + 39845888ull);          // [3][C,1024] 6.3MB
  float* clsH  = xitmp;                               // overlay (disjoint lifetime)
  float* igbuf = (float*)(ws + 46137344ull);          // [3][C,3072] 18.9MB
  half8* gw16  = (half8*)(ws + 65011712ull);          // scan frag cache 4.7MB
  float* bufY  = (float*)(ws + 69730304ull);          // [3][C,1024] 6.3MB
  float* bufH  = (float*)(ws + 76021760ull);          // [3][C,1024] 6.3MB
  float* hst   = (float*)(ws + 82313216ull);          // [3,4,256] 12KB
  _Float16* wf = (_Float16*)(ws + 82325504ull);       // f16 weights 35.9MB
  float* encS  = (float*)(ws + 118239232ull);         // encoder hidden 33.5MB

  // f16 weight sub-offsets (in halfs)
  _Float16* wh_enc1 = wf;                     // 1024x128
  _Float16* wh_enc2 = wf + 131072;            // 1024x1024
  _Float16* wh_wih  = wf + 1179648;           // 3x 3072x1024
  _Float16* wh_mw1  = wf + 10616832;          // 3x 1024x1024
  _Float16* wh_mw2  = wf + 13762560;          // 3x 1024x1024
  _Float16* wh_cw1  = wf + 16908288;          // 1024x1024

  const dim3 blk(256);
  const dim3 g_enc(8192 / 64, 1024 / 64);
  const dim3 g_ig_b(C_CH / 64, 3072 / 64, 3);
  const dim3 g_mlp_b(C_CH / 64, 1024 / 64, 3);
  const dim3 g_mlp(C_CH / 64, 1024 / 64);

  // scan frag cache + GEMM weight conversion
  prep_whh<<<dim3(1152), blk, 0, stream>>>(gwhh, gw16);
  cvt_to_h<<<dim3(64),   blk, 0, stream>>>(enc_w1, wh_enc1, 16384);
  cvt_to_h<<<dim3(512),  blk, 0, stream>>>(enc_w2, wh_enc2, 131072);
  cvt_to_h<<<dim3(4608), blk, 0, stream>>>(gwih,   wh_wih,  1179648);
  cvt_to_h<<<dim3(1536), blk, 0, stream>>>(mw1,    wh_mw1,  393216);
  cvt_to_h<<<dim3(1536), blk, 0, stream>>>(mw2,    wh_mw2,  393216);
  cvt_to_h<<<dim3(512),  blk, 0, stream>>>(cw1,    wh_cw1,  131072);

  // encoder (full T)
  gemm_h<0, true ><<<g_enc, blk, 0, stream>>>(inputs, wh_enc1, enc_b1, nullptr,
                                              encS, 8192, 1024, 128, nullptr);
  gemm_h<0, false><<<g_enc, blk, 0, stream>>>(encS, wh_enc2, enc_b2, nullptr,
                                              x0, 8192, 1024, 1024, nullptr);

  for (int d = 0; d < NDIAG; ++d) {
    // --- pre (batched over layers): xi = LN(x) ; ig = (xi@wih^T)/s + b ---
    ln_pre_b<<<dim3(3 * C_CH), blk, 0, stream>>>(x0, xn, xitmp, d);
    gemm_b<1, false><<<g_ig_b, blk, 0, stream>>>(
        xitmp, (size_t)C_CH * NST, wh_wih, 3145728ull, gb, 3072ull,
        nullptr, 0ull, igbuf, (size_t)C_CH * LD_IG, 3072, 1024, gls, d);
    // --- scan diagonal: up to 12 (layer,channel) blocks in parallel ---
    scan_diag<<<dim3(12), dim3(512), 0, stream>>>(gw16, gbn, gls, igbuf,
                                                  h0, hst, bufY, d);
    // --- post (batched): y = LN(y+xi) in-place; x_next = mlp(y) + y -> xn ---
    ln2_b<<<dim3(3 * C_CH), blk, 0, stream>>>(bufY, x0, xn, d);
    gemm_b<0, true ><<<g_mlp_b, blk, 0, stream>>>(
        bufY, (size_t)C_CH * NST, wh_mw1, 1048576ull, mb1, 1024ull,
        nullptr, 0ull, bufH, (size_t)C_CH * NST, 1024, 1024, nullptr, d);
    gemm_b<2, false><<<g_mlp_b, blk, 0, stream>>>(
        bufH, (size_t)C_CH * NST, wh_mw2, 1048576ull, mb2, 1024ull,
        bufY, (size_t)C_CH * NST, xn, (size_t)C_CH * NST, 1024, 1024, nullptr, d);
    // --- classifier on layer 2's finished chunk ---
    const int c2 = d - 2;
    if (0 <= c2 && c2 < NCHUNK) {
      gemm_h<0, true><<<g_mlp, blk, 0, stream>>>(
          xn + 2ull * C_CH * NST, wh_cw1, cb1, nullptr, clsH, C_CH, 1024, 1024, nullptr);
      gemv_cls<<<dim3(C_CH), blk, 0, stream>>>(clsH, cw2, cb2,
                                               out + (size_t)c2 * C_CH * 10);
    }
  }
}

// Round 18
// 10701.170 us; speedup vs baseline: 1.5151x; 1.0312x over previous
//
#include <hip/hip_runtime.h>

// MultiScaleGRU: T=8192, NINP=128, NSTATE=1024, NCH=4, GH=256, NLAYER=3, NCLASS=10
#define T_SEQ  8192
#define NST    1024
#define GHH    256
#define LD_IG  3072      // 4 channels * 768 ig columns
#define C_CH   512       // pipeline chunk length
#define NCHUNK 16
#define NDIAG  18        // NCHUNK + NLAYER - 1

typedef _Float16 half8 __attribute__((ext_vector_type(8)));
typedef float f32x4 __attribute__((ext_vector_type(4)));

#define MFMA16(a, b, c) __builtin_amdgcn_mfma_f32_16x16x32_f16(a, b, c, 0, 0, 0)

__device__ __forceinline__ float sigmoid_f(float x) {
  return 1.0f / (1.0f + __expf(-x));
}
__device__ __forceinline__ float tanh_f(float x) {
  float ax = fabsf(x);
  float e = __expf(-2.0f * ax);
  float t = (1.0f - e) / (1.0f + e);
  return copysignf(t, x);
}

// layer z's input chunk: layer 0 reads the persistent x0; layers 1,2 read the
// single-slot xn[z-1] (produced at post(d-1), consumed only at pre/post(d))
__device__ __forceinline__ const float* xin_ptr(const float* x0, const float* xn,
                                                int z, int c) {
  return (z == 0) ? x0 + (size_t)c * C_CH * NST
                  : xn + (size_t)(z - 1) * C_CH * NST;
}

// ---------------------------------------------------------------------------
// Prep: whh [3,4,768,256] f32 -> f16 MFMA B-fragment cache (R7/R10-verified).
// ---------------------------------------------------------------------------
__global__ __launch_bounds__(256) void prep_whh(const float* __restrict__ whh,
                                                half8* __restrict__ wB)
{
  const int idx = blockIdx.x * 256 + threadIdx.x;   // 0 .. 294911
  const int lc  = idx / 24576;                      // layer*4+ch
  const int rem = idx - lc * 24576;
  const int g_id = rem >> 6, l = rem & 63;
  const int nb = g_id >> 3, kc = g_id & 7;
  const int g = nb >> 4, ub = nb & 15;
  const int n = l & 15, kg = l >> 4;
  const int row = g * 256 + ub * 16 + n;
  const int col = kc * 32 + kg * 8;
  const float* src = whh + (size_t)lc * 196608 + (size_t)row * 256 + col;
  float4 x0 = *reinterpret_cast<const float4*>(src);
  float4 x1 = *reinterpret_cast<const float4*>(src + 4);
  half8 o;
  o[0] = (_Float16)x0.x; o[1] = (_Float16)x0.y;
  o[2] = (_Float16)x0.z; o[3] = (_Float16)x0.w;
  o[4] = (_Float16)x1.x; o[5] = (_Float16)x1.y;
  o[6] = (_Float16)x1.z; o[7] = (_Float16)x1.w;
  wB[idx] = o;
}

// ---------------------------------------------------------------------------
// Weight f32 -> f16 converter (row-major, layout-preserving). n8 = elems/8.
// ---------------------------------------------------------------------------
__global__ __launch_bounds__(256) void cvt_to_h(const float* __restrict__ src,
                                                _Float16* __restrict__ dst, int n8)
{
  const int i = blockIdx.x * 256 + threadIdx.x;
  if (i >= n8) return;
  float4 a = reinterpret_cast<const float4*>(src)[2 * i];
  float4 b = reinterpret_cast<const float4*>(src)[2 * i + 1];
  half8 o;
  o[0] = (_Float16)a.x; o[1] = (_Float16)a.y; o[2] = (_Float16)a.z; o[3] = (_Float16)a.w;
  o[4] = (_Float16)b.x; o[5] = (_Float16)b.y; o[6] = (_Float16)b.z; o[7] = (_Float16)b.w;
  reinterpret_cast<half8*>(dst)[i] = o;
}

// ---------------------------------------------------------------------------
// f16-MFMA GEMM tile body (R11-verified math): C = epi(A @ Wh^T).
// ---------------------------------------------------------------------------
template<int EPI, bool RELU>
__device__ __forceinline__ void gemm_body(
    const float* __restrict__ A, const _Float16* __restrict__ Wh,
    const float* __restrict__ bias, const float* __restrict__ R,
    float* __restrict__ C, int N, int K, const float* __restrict__ log_s,
    int bm, int bn, _Float16 (*As)[40], _Float16 (*Ws)[40])
{
  const int t = threadIdx.x;
  const int wave = t >> 6, l = t & 63;
  const int wm = (wave & 1) * 32, wn = (wave >> 1) * 32;
  const int sr = t >> 2, sc = (t & 3) * 8;
  const int fr = l & 15, fk = (l >> 4) * 8;

  f32x4 acc00 = {0.f, 0.f, 0.f, 0.f}, acc01 = acc00, acc10 = acc00, acc11 = acc00;

  const float* Ap     = A  + (size_t)(bm + sr) * K + sc;
  const _Float16* Wp  = Wh + (size_t)(bn + sr) * K + sc;

  for (int k0 = 0; k0 < K; k0 += 32) {
    float4 a0 = *reinterpret_cast<const float4*>(Ap + k0);
    float4 a1 = *reinterpret_cast<const float4*>(Ap + k0 + 4);
    half8 av;
    av[0] = (_Float16)a0.x; av[1] = (_Float16)a0.y;
    av[2] = (_Float16)a0.z; av[3] = (_Float16)a0.w;
    av[4] = (_Float16)a1.x; av[5] = (_Float16)a1.y;
    av[6] = (_Float16)a1.z; av[7] = (_Float16)a1.w;
    *reinterpret_cast<half8*>(&As[sr][sc]) = av;
    *reinterpret_cast<half8*>(&Ws[sr][sc]) =
        *reinterpret_cast<const half8*>(Wp + k0);
    __syncthreads();
    half8 af0 = *reinterpret_cast<const half8*>(&As[wm + fr][fk]);
    half8 af1 = *reinterpret_cast<const half8*>(&As[wm + 16 + fr][fk]);
    half8 bf0 = *reinterpret_cast<const half8*>(&Ws[wn + fr][fk]);
    half8 bf1 = *reinterpret_cast<const half8*>(&Ws[wn + 16 + fr][fk]);
    acc00 = MFMA16(af0, bf0, acc00);
    acc01 = MFMA16(af0, bf1, acc01);
    acc10 = MFMA16(af1, bf0, acc10);
    acc11 = MFMA16(af1, bf1, acc11);
    __syncthreads();
  }

#define EPI_STORE(ac, mi, ni) { \
    const int n_ = bn + wn + (ni) * 16 + fr; \
    const float bv = bias[n_]; \
    float sc_ = 1.f; \
    if (EPI == 1) { \
      float lsv = log_s[n_ / 768]; \
      lsv = fminf(fmaxf(lsv, -10.f), 10.f); \
      sc_ = __expf(-lsv); \
    } \
    _Pragma("unroll") \
    for (int q = 0; q < 4; ++q) { \
      const int m_ = bm + wm + (mi) * 16 + (l >> 4) * 4 + q; \
      float v = ac[q]; \
      if (EPI == 1) v *= sc_; \
      v += bv; \
      if (EPI == 2) v += R[(size_t)m_ * N + n_]; \
      if (RELU) v = fmaxf(v, 0.f); \
      C[(size_t)m_ * N + n_] = v; \
    } }
  EPI_STORE(acc00, 0, 0) EPI_STORE(acc01, 0, 1)
  EPI_STORE(acc10, 1, 0) EPI_STORE(acc11, 1, 1)
#undef EPI_STORE
}

// standalone (encoder / tail classifier)
template<int EPI, bool RELU>
__global__ __launch_bounds__(256) void gemm_h(
    const float* __restrict__ A, const _Float16* __restrict__ Wh,
    const float* __restrict__ bias, const float* __restrict__ R,
    float* __restrict__ C, int M, int N, int K,
    const float* __restrict__ log_s)
{
  __shared__ _Float16 As[64][40];
  __shared__ _Float16 Ws[64][40];
  gemm_body<EPI, RELU>(A, Wh, bias, R, C, N, K, log_s,
                       blockIdx.x * 64, blockIdx.y * 64, As, Ws);
}

// z-batched over layers: per-z strides; inactive (layer,chunk) pairs exit.
template<int EPI, bool RELU>
__global__ __launch_bounds__(256) void gemm_b(
    const float* __restrict__ Abase, size_t Astride,
    const _Float16* __restrict__ Wbase, size_t Wstride,
    const float* __restrict__ bbase, size_t bstride,
    const float* __restrict__ Rbase, size_t Rstride,
    float* __restrict__ Cbase, size_t Cstride,
    int N, int K, const float* __restrict__ lsbase, int d)
{
  const int z = blockIdx.z;
  if ((unsigned)(d - z) >= NCHUNK) return;
  __shared__ _Float16 As[64][40];
  __shared__ _Float16 Ws[64][40];
  gemm_body<EPI, RELU>(Abase + (size_t)z * Astride, Wbase + (size_t)z * Wstride,
                       bbase + (size_t)z * bstride,
                       Rbase ? Rbase + (size_t)z * Rstride : nullptr,
                       Cbase + (size_t)z * Cstride, N, K,
                       lsbase ? lsbase + (size_t)z * 4 : nullptr,
                       blockIdx.x * 64, blockIdx.y * 64, As, Ws);
}

// mlp1 (z=0..2) + classifier slice (z=3, chunk d-3 from xn[2], which this
// diagonal's mlp2 has not yet overwritten). Both are EPI0 + RELU.
__global__ __launch_bounds__(256) void gemm_mlp1_cls(
    const float* __restrict__ bufY, const _Float16* __restrict__ mw1h,
    const float* __restrict__ mb1h, float* __restrict__ bufH,
    const float* __restrict__ xn2, const _Float16* __restrict__ cw1h,
    const float* __restrict__ cb1h, float* __restrict__ clsF, int d)
{
  const int z = blockIdx.z;
  __shared__ _Float16 As[64][40];
  __shared__ _Float16 Ws[64][40];
  if (z < 3) {
    if ((unsigned)(d - z) >= NCHUNK) return;
    gemm_body<0, true>(bufY + (size_t)z * C_CH * NST, mw1h + (size_t)z * 1048576,
                       mb1h + (size_t)z * 1024, nullptr,
                       bufH + (size_t)z * C_CH * NST, 1024, 1024, nullptr,
                       blockIdx.x * 64, blockIdx.y * 64, As, Ws);
  } else {
    const int cc = d - 3;
    if ((unsigned)cc >= NCHUNK) return;
    gemm_body<0, true>(xn2, cw1h, cb1h, nullptr,
                       clsF + (size_t)cc * C_CH * NST, 1024, 1024, nullptr,
                       blockIdx.x * 64, blockIdx.y * 64, As, Ws);
  }
}

// ---------------------------------------------------------------------------
// Batched pre-LN: O[z] = LN(xin(z, d-z)) for active layers. grid = 3*C_CH.
// ---------------------------------------------------------------------------
__global__ __launch_bounds__(256) void ln_pre_b(const float* __restrict__ x0,
                                                const float* __restrict__ xn,
                                                float* __restrict__ O, int d)
{
  const int z = blockIdx.x >> 9, row = blockIdx.x & 511;
  const int c = d - z;
  if ((unsigned)c >= NCHUNK) return;
  const int t = threadIdx.x;
  const float* X = xin_ptr(x0, xn, z, c) + (size_t)row * NST;
  float4 v = reinterpret_cast<const float4*>(X)[t];
  float s  = v.x + v.y + v.z + v.w;
  float ss = v.x * v.x + v.y * v.y + v.z * v.z + v.w * v.w;
#pragma unroll
  for (int m = 1; m < 64; m <<= 1) {
    s += __shfl_xor(s, m, 64); ss += __shfl_xor(ss, m, 64);
  }
  __shared__ float ps[4], pss[4];
  const int wv = t >> 6;
  if ((t & 63) == 0) { ps[wv] = s; pss[wv] = ss; }
  __syncthreads();
  s  = ps[0] + ps[1] + ps[2] + ps[3];
  ss = pss[0] + pss[1] + pss[2] + pss[3];
  const float mean = s * (1.f / 1024.f);
  const float var  = ss * (1.f / 1024.f) - mean * mean;
  const float rstd = rsqrtf(var + 1e-5f);
  v.x = (v.x - mean) * rstd; v.y = (v.y - mean) * rstd;
  v.z = (v.z - mean) * rstd; v.w = (v.w - mean) * rstd;
  reinterpret_cast<float4*>(O + ((size_t)z * C_CH + row) * NST)[t] = v;
}

// ---------------------------------------------------------------------------
// Batched fused double-LN, IN-PLACE in Y: Y[z] = LN(Y[z] + LN(xin(z,d-z))).
// ---------------------------------------------------------------------------
__global__ __launch_bounds__(256) void ln2_b(float* __restrict__ Y,
                                             const float* __restrict__ x0,
                                             const float* __restrict__ xn,
                                             int d)
{
  const int z = blockIdx.x >> 9, row = blockIdx.x & 511;
  const int c = d - z;
  if ((unsigned)c >= NCHUNK) return;
  const int t = threadIdx.x;
  const int wv = t >> 6;
  __shared__ float ps[4], pss[4], ps2[4], pss2[4];

  const float* X = xin_ptr(x0, xn, z, c) + (size_t)row * NST;
  float* Yr = Y + ((size_t)z * C_CH + row) * NST;

  float4 xv = reinterpret_cast<const float4*>(X)[t];
  float s  = xv.x + xv.y + xv.z + xv.w;
  float ss = xv.x * xv.x + xv.y * xv.y + xv.z * xv.z + xv.w * xv.w;
#pragma unroll
  for (int m = 1; m < 64; m <<= 1) {
    s += __shfl_xor(s, m, 64); ss += __shfl_xor(ss, m, 64);
  }
  if ((t & 63) == 0) { ps[wv] = s; pss[wv] = ss; }
  __syncthreads();
  s = ps[0] + ps[1] + ps[2] + ps[3];
  ss = pss[0] + pss[1] + pss[2] + pss[3];
  float mean = s * (1.f / 1024.f);
  float var  = ss * (1.f / 1024.f) - mean * mean;
  float rstd = rsqrtf(var + 1e-5f);

  float4 yv = reinterpret_cast<const float4*>(Yr)[t];
  float4 v;
  v.x = yv.x + (xv.x - mean) * rstd;
  v.y = yv.y + (xv.y - mean) * rstd;
  v.z = yv.z + (xv.z - mean) * rstd;
  v.w = yv.w + (xv.w - mean) * rstd;

  s  = v.x + v.y + v.z + v.w;
  ss = v.x * v.x + v.y * v.y + v.z * v.z + v.w * v.w;
#pragma unroll
  for (int m = 1; m < 64; m <<= 1) {
    s += __shfl_xor(s, m, 64); ss += __shfl_xor(ss, m, 64);
  }
  if ((t & 63) == 0) { ps2[wv] = s; pss2[wv] = ss; }
  __syncthreads();
  s = ps2[0] + ps2[1] + ps2[2] + ps2[3];
  ss = pss2[0] + pss2[1] + pss2[2] + pss2[3];
  mean = s * (1.f / 1024.f);
  var  = ss * (1.f / 1024.f) - mean * mean;
  rstd = rsqrtf(var + 1e-5f);
  v.x = (v.x - mean) * rstd; v.y = (v.y - mean) * rstd;
  v.z = (v.z - mean) * rstd; v.w = (v.w - mean) * rstd;
  reinterpret_cast<float4*>(Yr)[t] = v;
}

// ---------------------------------------------------------------------------
// ScaleGRU scan — diagonal MFMA, gate-in-wave v3 (UNCHANGED from R15-R17,
// verified: 2400 cy/step, 0.512 ms/dispatch, absmax 0.0625).
// ---------------------------------------------------------------------------
#define SCAN_BAR() asm volatile("s_waitcnt lgkmcnt(0)\n\ts_barrier" ::: "memory")

#define DECLB(i) half8 B##i##_0, B##i##_1, B##i##_2, B##i##_3, \
                       B##i##_4, B##i##_5, B##i##_6, B##i##_7;
#define LOADBn(i, nb) \
  B##i##_0 = wpB[((nb)*8+0)*64]; B##i##_1 = wpB[((nb)*8+1)*64]; \
  B##i##_2 = wpB[((nb)*8+2)*64]; B##i##_3 = wpB[((nb)*8+3)*64]; \
  B##i##_4 = wpB[((nb)*8+4)*64]; B##i##_5 = wpB[((nb)*8+5)*64]; \
  B##i##_6 = wpB[((nb)*8+6)*64]; B##i##_7 = wpB[((nb)*8+7)*64];

#define KCSTEP(kc) { \
  half8 a = hp[(kc) * 4]; \
  a0 = MFMA16(a, B0_##kc, a0); a1 = MFMA16(a, B1_##kc, a1); \
  a2 = MFMA16(a, B2_##kc, a2); a3 = MFMA16(a, B3_##kc, a3); \
  a4 = MFMA16(a, B4_##kc, a4); a5 = MFMA16(a, B5_##kc, a5); }

__global__ __attribute__((amdgpu_flat_work_group_size(512, 512)))
void scan_diag(
    const half8* __restrict__ wB,     // frag cache [3*4][384][64]
    const float* __restrict__ gbn,    // [3,4,256]
    const float* __restrict__ gls,    // [3,4]
    const float* __restrict__ igb,    // [3][C_CH,3072]
    const float* __restrict__ h0,     // [256]
    float* __restrict__ hst,          // [3*4*256] carried h state
    float* __restrict__ yb,           // [3][C_CH,1024]
    int d)
{
  const int lidx = blockIdx.x >> 2;
  const int ch   = blockIdx.x & 3;
  const int c    = d - lidx;
  if (c < 0 || c >= NCHUNK) return;

  const int j = threadIdx.x;
  const int w = j >> 6, l = j & 63;
  const int lc = lidx * 4 + ch;
  const float* igc = igb + (size_t)lidx * (C_CH * LD_IG) + ch * 768;
  float* yc        = yb + (size_t)lidx * (C_CH * NST) + ch * GHH;

  const half8* wpB = wB + (size_t)lc * 24576 + l;
  DECLB(0) DECLB(1) DECLB(2) DECLB(3) DECLB(4) DECLB(5)
  LOADBn(0, w)      LOADBn(1, w + 8)  LOADBn(2, w + 16)
  LOADBn(3, w + 24) LOADBn(4, w + 32) LOADBn(5, w + 40)

  __shared__ __align__(16) _Float16 hsl[2][GHH];   // double-buffered h

  const bool glane = (l < 32);
  const bool hi    = (l & 16) != 0;
  const int u = 16 * w + (l & 15) + (hi ? 128 : 0);

  float ls = gls[lc];
  ls = fminf(fmaxf(ls, -10.f), 10.f);
  const float inv_s = __expf(-ls);
  float bnu = 0.f, h = 0.f, ir = 0.f, iz = 0.f, in_ = 0.f;
  if (glane) {
    h   = (c == 0) ? h0[u] : hst[lc * GHH + u];
    bnu = gbn[lc * GHH + u];
    hsl[0][u] = (_Float16)h;
    ir = igc[u]; iz = igc[256 + u]; in_ = igc[512 + u];
  }
  SCAN_BAR();

  for (int t = 0; t < C_CH; ++t) {
    float nr = 0.f, nz = 0.f, nn = 0.f;
    if (glane && t + 1 < C_CH) {
      const float* p = igc + (size_t)(t + 1) * LD_IG;
      nr = p[u]; nz = p[256 + u]; nn = p[512 + u];
    }
    const half8* hp = reinterpret_cast<const half8*>(hsl[t & 1]) + (l >> 4);
    f32x4 a0 = {0.f, 0.f, 0.f, 0.f}, a1 = a0, a2 = a0, a3 = a0, a4 = a0, a5 = a0;
    KCSTEP(0) KCSTEP(1) KCSTEP(2) KCSTEP(3)
    KCSTEP(4) KCSTEP(5) KCSTEP(6) KCSTEP(7)
    if (glane) {
      const float pr = hi ? a1[0] : a0[0];
      const float pz = hi ? a3[0] : a2[0];
      const float pn = hi ? a5[0] : a4[0];
      const float rg = sigmoid_f(ir + pr);
      const float zg = sigmoid_f(iz + pz);
      const float ng = tanh_f(in_ + rg * (pn + bnu));
      const float hw = ng + zg * (h - ng);
      h = (hw - h) * inv_s + h;
      yc[(size_t)t * NST + u] = h;
      hsl[(t + 1) & 1][u] = (_Float16)h;
    }
    SCAN_BAR();
    ir = nr; iz = nz; in_ = nn;
  }
  if (glane) hst[lc * GHH + u] = h;
}

// ---------------------------------------------------------------------------
// Classifier second GEMM: N=10, K=1024. One block per row. Runs ONCE over
// all T rows at the end (clsF is complete by then).
// ---------------------------------------------------------------------------
__global__ __launch_bounds__(256) void gemv_cls(const float* __restrict__ A,
                                                const float* __restrict__ W,
                                                const float* __restrict__ b,
                                                float* __restrict__ out)
{
  const int m = blockIdx.x, t = threadIdx.x;
  float4 a = reinterpret_cast<const float4*>(A + (size_t)m * NST)[t];
  float p[10];
#pragma unroll
  for (int n = 0; n < 10; ++n) {
    float4 w = reinterpret_cast<const float4*>(W + (size_t)n * NST)[t];
    p[n] = a.x * w.x + a.y * w.y + a.z * w.z + a.w * w.w;
  }
#pragma unroll
  for (int n = 0; n < 10; ++n)
#pragma unroll
    for (int msk = 1; msk < 64; msk <<= 1) p[n] += __shfl_xor(p[n], msk, 64);
  __shared__ float red[4][10];
  const int wv = t >> 6;
  if ((t & 63) == 0) {
#pragma unroll
    for (int n = 0; n < 10; ++n) red[wv][n] = p[n];
  }
  __syncthreads();
  if (t < 10) {
    float v = red[0][t] + red[1][t] + red[2][t] + red[3][t] + b[t];
    out[(size_t)m * 10 + t] = v;
  }
}

// ---------------------------------------------------------------------------
extern "C" void kernel_launch(void* const* d_in, const int* in_sizes, int n_in,
                              void* d_out, int out_size, void* d_ws, size_t ws_size,
                              hipStream_t stream) {
  const float* inputs = (const float*)d_in[0];
  const float* h0     = (const float*)d_in[1];
  // d_in[2] = yinit_guess: unused (exact solution independent of it)
  const float* enc_w1 = (const float*)d_in[3];
  const float* enc_b1 = (const float*)d_in[4];
  const float* enc_w2 = (const float*)d_in[5];
  const float* enc_b2 = (const float*)d_in[6];
  const float* gwih   = (const float*)d_in[7];   // [3,4,768,1024]
  const float* gwhh   = (const float*)d_in[8];   // [3,4,768,256]
  const float* gb     = (const float*)d_in[9];   // [3,4,768]
  const float* gbn    = (const float*)d_in[10];  // [3,4,256]
  const float* gls    = (const float*)d_in[11];  // [3,4,1]
  const float* mw1    = (const float*)d_in[12];
  const float* mb1    = (const float*)d_in[13];
  const float* mw2    = (const float*)d_in[14];
  const float* mb2    = (const float*)d_in[15];
  const float* cw1    = (const float*)d_in[16];
  const float* cb1    = (const float*)d_in[17];
  const float* cw2    = (const float*)d_in[18];
  const float* cb2    = (const float*)d_in[19];
  float* out = (float*)d_out;

  // ws layout (bytes) — tops out at 151.8MB (< 162.3MB proven). clsF overlays
  // encS (encoder hidden, dead after the encoder GEMMs).
  char* ws = (char*)d_ws;
  float* x0    = (float*)(ws);                        // [8192,1024] 33.5MB
  float* xn    = (float*)(ws + 33554432ull);          // [3][C,1024] 6.3MB
  float* xitmp = (float*)(ws + 39845888ull);          // [3][C,1024] 6.3MB
  float* igbuf = (float*)(ws + 46137344ull);          // [3][C,3072] 18.9MB
  half8* gw16  = (half8*)(ws + 65011712ull);          // scan frag cache 4.7MB
  float* bufY  = (float*)(ws + 69730304ull);          // [3][C,1024] 6.3MB
  float* bufH  = (float*)(ws + 76021760ull);          // [3][C,1024] 6.3MB
  float* hst   = (float*)(ws + 82313216ull);          // [3,4,256] 12KB
  _Float16* wf = (_Float16*)(ws + 82325504ull);       // f16 weights 35.9MB
  float* encS  = (float*)(ws + 118239232ull);         // enc hidden 33.5MB
  float* clsF  = encS;                                 // [8192,1024] overlay

  // f16 weight sub-offsets (in halfs)
  _Float16* wh_enc1 = wf;                     // 1024x128
  _Float16* wh_enc2 = wf + 131072;            // 1024x1024
  _Float16* wh_wih  = wf + 1179648;           // 3x 3072x1024
  _Float16* wh_mw1  = wf + 10616832;          // 3x 1024x1024
  _Float16* wh_mw2  = wf + 13762560;          // 3x 1024x1024
  _Float16* wh_cw1  = wf + 16908288;          // 1024x1024

  const dim3 blk(256);
  const dim3 g_enc(8192 / 64, 1024 / 64);
  const dim3 g_ig_b(C_CH / 64, 3072 / 64, 3);
  const dim3 g_mlp_b(C_CH / 64, 1024 / 64, 3);
  const dim3 g_mlp1c(C_CH / 64, 1024 / 64, 4);
  const dim3 g_mlp(C_CH / 64, 1024 / 64);

  // scan frag cache + GEMM weight conversion
  prep_whh<<<dim3(1152), blk, 0, stream>>>(gwhh, gw16);
  cvt_to_h<<<dim3(64),   blk, 0, stream>>>(enc_w1, wh_enc1, 16384);
  cvt_to_h<<<dim3(512),  blk, 0, stream>>>(enc_w2, wh_enc2, 131072);
  cvt_to_h<<<dim3(4608), blk, 0, stream>>>(gwih,   wh_wih,  1179648);
  cvt_to_h<<<dim3(1536), blk, 0, stream>>>(mw1,    wh_mw1,  393216);
  cvt_to_h<<<dim3(1536), blk, 0, stream>>>(mw2,    wh_mw2,  393216);
  cvt_to_h<<<dim3(512),  blk, 0, stream>>>(cw1,    wh_cw1,  131072);

  // encoder (full T)
  gemm_h<0, true ><<<g_enc, blk, 0, stream>>>(inputs, wh_enc1, enc_b1, nullptr,
                                              encS, 8192, 1024, 128, nullptr);
  gemm_h<0, false><<<g_enc, blk, 0, stream>>>(encS, wh_enc2, enc_b2, nullptr,
                                              x0, 8192, 1024, 1024, nullptr);

  for (int d = 0; d < NDIAG; ++d) {
    // --- pre (batched over layers): xi = LN(x) ; ig = (xi@wih^T)/s + b ---
    ln_pre_b<<<dim3(3 * C_CH), blk, 0, stream>>>(x0, xn, xitmp, d);
    gemm_b<1, false><<<g_ig_b, blk, 0, stream>>>(
        xitmp, (size_t)C_CH * NST, wh_wih, 3145728ull, gb, 3072ull,
        nullptr, 0ull, igbuf, (size_t)C_CH * LD_IG, 3072, 1024, gls, d);
    // --- scan diagonal: up to 12 (layer,channel) blocks in parallel ---
    scan_diag<<<dim3(12), dim3(512), 0, stream>>>(gw16, gbn, gls, igbuf,
                                                  h0, hst, bufY, d);
    // --- post (batched): y = LN(y+xi) in-place; mlp1 (+ cls slice for
    //     chunk d-3, reading xn[2] before this diagonal's mlp2 rewrites it);
    //     mlp2 -> xn ---
    ln2_b<<<dim3(3 * C_CH), blk, 0, stream>>>(bufY, x0, xn, d);
    gemm_mlp1_cls<<<g_mlp1c, blk, 0, stream>>>(
        bufY, wh_mw1, mb1, bufH, xn + 2ull * C_CH * NST, wh_cw1, cb1, clsF, d);
    gemm_b<2, false><<<g_mlp_b, blk, 0, stream>>>(
        bufH, (size_t)C_CH * NST, wh_mw2, 1048576ull, mb2, 1024ull,
        bufY, (size_t)C_CH * NST, xn, (size_t)C_CH * NST, 1024, 1024, nullptr, d);
  }
  // tail: classifier GEMM for the last chunk (xn[2] holds chunk 15 after
  // d=17's mlp2), then one batched gemv over all T rows.
  gemm_h<0, true><<<g_mlp, blk, 0, stream>>>(
      xn + 2ull * C_CH * NST, wh_cw1, cb1, nullptr,
      clsF + 15ull * C_CH * NST, C_CH, 1024, 1024, nullptr);
  gemv_cls<<<dim3(8192), blk, 0, stream>>>(clsF, cw2, cb2, out);
}